// Round 15
// baseline (69.859 us; speedup 1.0000x reference)
//
#include <hip/hip_runtime.h>
#include <hip/hip_bf16.h>
#include <math.h>

#define H    16
#define HKV  4
#define G    4
#define NN   2048
#define D    64
#define HID  1024
#define CB   16
#define W    128
#define NSEL 4
#define WIN  64
#define NEGV -1e10f
#define SCALE 0.125f

typedef __attribute__((ext_vector_type(4))) float f32x4;
typedef __attribute__((ext_vector_type(4))) short short4v;
typedef __attribute__((ext_vector_type(8))) short short8v;

__device__ inline short f2b(float x){
    __hip_bfloat16 h = __float2bfloat16(x);
    return *reinterpret_cast<short*>(&h);
}
__device__ inline float b2f(short s){
    unsigned u = ((unsigned)(unsigned short)s) << 16;
    return __builtin_bit_cast(float, u);
}
__device__ inline short8v cvt8(f32x4 a, f32x4 b){
    short8v r;
    r[0]=f2b(a[0]); r[1]=f2b(a[1]); r[2]=f2b(a[2]); r[3]=f2b(a[3]);
    r[4]=f2b(b[0]); r[5]=f2b(b[1]); r[6]=f2b(b[2]); r[7]=f2b(b[3]);
    return r;
}
#define SWZ(byte, row) ((byte) ^ (((row)&7)<<4))
#define MFMA(a,b,c) __builtin_amdgcn_mfma_f32_16x16x32_bf16(a,b,c,0,0,0)

__device__ inline float wave_sum(float x){ for(int o=32;o;o>>=1) x += __shfl_xor(x,o); return x; }

__device__ inline f32x4 vmax4(f32x4 a, f32x4 b){
    f32x4 r; r[0]=fmaxf(a[0],b[0]); r[1]=fmaxf(a[1],b[1]); r[2]=fmaxf(a[2],b[2]); r[3]=fmaxf(a[3],b[3]); return r;
}
__device__ inline f32x4 shflx4(f32x4 x, int o){
    f32x4 r; r[0]=__shfl_xor(x[0],o); r[1]=__shfl_xor(x[1],o); r[2]=__shfl_xor(x[2],o); r[3]=__shfl_xor(x[3],o); return r;
}
__device__ inline f32x4 exp4(f32x4 x){
    f32x4 r; r[0]=expf(x[0]); r[1]=expf(x[1]); r[2]=expf(x[2]); r[3]=expf(x[3]); return r;
}

// ---------------------------------------------------------------------------
// K1: fused prep. 848 blocks.
__device__ inline void conv_seg(const float* __restrict__ src, short* __restrict__ dst,
                                int b, int t){
    size_t idx = (size_t)b*1024 + t*4;
    f32x4 a = *(const f32x4*)(src + idx);
    short4v r; r[0]=f2b(a[0]); r[1]=f2b(a[1]); r[2]=f2b(a[2]); r[3]=f2b(a[3]);
    *(short4v*)(dst + idx) = r;
}

__global__ __launch_bounds__(256) void k_prep(
    const float* __restrict__ combiner_w,
    const float* __restrict__ k, const float* __restrict__ v,
    const float* __restrict__ memkv, const float* __restrict__ ksc, const float* __restrict__ vsc,
    short* __restrict__ cwb, short* __restrict__ kb16,
    short* __restrict__ vT, short* __restrict__ ckb, short* __restrict__ cvtg)
{
    int b = blockIdx.x, t = threadIdx.x;
    if (b < 48){ conv_seg(combiner_w, cwb, b, t); return; }
    b -= 48;
    if (b < 512){ conv_seg(k, kb16, b, t); return; }
    b -= 512;
    if (b < 128){
        __shared__ float tl[64][65];
        int hk = b>>5, i0 = (b&31)*64;
        for (int u=0;u<4;u++){
            int cid = t + 256*u; int r = cid>>4, ch = cid&15;
            f32x4 a = *(const f32x4*)(v + ((size_t)(hk*NN + i0 + r))*D + ch*4);
            tl[r][ch*4+0]=a[0]; tl[r][ch*4+1]=a[1]; tl[r][ch*4+2]=a[2]; tl[r][ch*4+3]=a[3];
        }
        __syncthreads();
        int d = t>>2, qd = t&3;
        short8v p0, p1;
        #pragma unroll
        for (int e=0;e<8;e++) p0[e] = f2b(tl[qd*16+e][d]);
        #pragma unroll
        for (int e=0;e<8;e++) p1[e] = f2b(tl[qd*16+8+e][d]);
        short* dst = vT + ((size_t)(hk*64 + d))*NN + i0 + qd*16;
        *(short8v*)dst = p0;
        *(short8v*)(dst+8) = p1;
        return;
    }
    b -= 128;
    {
        int j = b;
        int hk = t>>6, d = t&63;
        if (j > 128){
            if (j < 144) ckb[((size_t)(hk*144 + j))*64 + d] = 0;
            cvtg[((size_t)(hk*64 + d))*160 + j] = 0;
            return;
        }
        float xk, xv;
        if (j==0){ xk = memkv[(0*HKV+hk)*D + d]; xv = memkv[(HKV+hk)*D + d]; }
        else {
            int jb = j-1;
            const float* kp = k + ((size_t)(hk*NN + jb*CB))*D + d;
            const float* vp = v + ((size_t)(hk*NN + jb*CB))*D + d;
            float sk=0.f, sv=0.f;
            #pragma unroll
            for (int tt=0;tt<CB;tt++){ sk += kp[tt*D]; sv += vp[tt*D]; }
            xk = sk*(1.0f/CB); xv = sv*(1.0f/CB);
            float msk = wave_sum(xk*xk)*(1.0f/D);
            float msv = wave_sum(xv*xv)*(1.0f/D);
            xk = xk*rsqrtf(msk+1e-6f)*ksc[d];
            xv = xv*rsqrtf(msv+1e-6f)*vsc[d];
        }
        ckb[((size_t)(hk*144 + j))*64 + d] = f2b(xk);
        cvtg[((size_t)(hk*64 + d))*160 + j] = f2b(xv);
    }
}

// ---------------------------------------------------------------------------
// K2: fused attention stage. B operands (CK, K-window, CV^T, V^T, CW) read DIRECT
// from L1/L2-hot global -> pl/impl/psl become wave-private -> 1 barrier per branch.
// cattn (0..511) + swin (512..1023) + gates split-K (1024..1151) + conv tail (1152..2175).
__global__ __launch_bounds__(256, 4) void k_attn(
    const float* __restrict__ q, const short* __restrict__ ckb, const short* __restrict__ cvt_g,
    short* __restrict__ outc, int* __restrict__ selidx,
    const short* __restrict__ kb16, const short* __restrict__ vTg, short* __restrict__ outs,
    const float* __restrict__ hidden, const short* __restrict__ cwb,
    float* __restrict__ gpart,
    const float* __restrict__ combine_w, short* __restrict__ wbg)
{
    __shared__ char smem[37120];
    int b = blockIdx.x, t = threadIdx.x;
    int w = t>>6, lane = t&63, c = lane&15, lg = lane>>4;

    if (b >= 1152){ conv_seg(combine_w, wbg, b - 1152, t); return; }

    if (b < 512){
        // ============ compressed attention + importance + top-k (1 barrier) ========
        char* aq  = smem;                      // 8192
        char* pl  = smem + 8192;               // 64*320 = 20480 (ends 28672)
        float* impl = (float*)(smem + 28672);  // 8192 (ends 36864)
        float* psl  = (float*)(smem + 36864);  // 256
        int hk = b & 3, i0 = (b >> 2)*16;
        const short* ckhk = ckb + (size_t)hk*144*64;
        const short* cvhk = cvt_g + (size_t)hk*64*160;

        for (int u=0;u<2;u++){
            int cid = t + 256*u; int row = cid>>3, ch = cid&7;
            const float* src = q + ((size_t)((hk*G + (row&3))*NN + i0 + (row>>2)))*D + ch*8;
            f32x4 a = *(const f32x4*)src, bb2 = *(const f32x4*)(src+4);
            *(short8v*)(aq + SWZ(row*128 + ch*16, row)) = cvt8(a,bb2);
        }
        __syncthreads();

        f32x4 acc[9];
        #pragma unroll
        for (int ct=0;ct<9;ct++) acc[ct] = (f32x4)0.f;
        #pragma unroll
        for (int ks=0;ks<2;ks++){
            int arow = w*16 + c;
            short8v af = *(short8v*)(aq + SWZ(arow*128 + ks*64 + lg*16, arow));
            #pragma unroll
            for (int ct=0;ct<9;ct++){
                int row = ct*16 + c;
                short8v bf = *(const short8v*)(ckhk + (size_t)row*64 + ks*32 + lg*8);
                acc[ct] = MFMA(af, bf, acc[ct]);
            }
        }

        f32x4 sum;
        {
            int tloc = w*4 + lg;
            int ii = i0 + tloc;
            #pragma unroll
            for (int ct=0;ct<9;ct++){
                int j = ct*16 + c;
                bool vis = (j==0) || (j<=128 && j*16 <= ii);
                f32x4 s = acc[ct]*SCALE;
                if (!vis){ s[0]=NEGV; s[1]=NEGV; s[2]=NEGV; s[3]=NEGV; }
                acc[ct] = s;
            }
            #pragma unroll
            for (int ct=0;ct<9;ct++){
                int j = ct*16 + c;
                if (j>=1 && j<=128){
                    f32x4 s = acc[ct];
                    impl[tloc*128 + (j-1)] = 0.25f*(s[0]+s[1]+s[2]+s[3]);
                }
            }
            f32x4 mx = acc[0];
            #pragma unroll
            for (int ct=1;ct<9;ct++) mx = vmax4(mx, acc[ct]);
            #pragma unroll
            for (int o=1;o<16;o<<=1) mx = vmax4(mx, shflx4(mx,o));
            sum = (f32x4)0.f;
            #pragma unroll
            for (int ct=0;ct<9;ct++){ acc[ct] = exp4(acc[ct]-mx); sum += acc[ct]; }
            #pragma unroll
            for (int o=1;o<16;o<<=1) sum += shflx4(sum,o);
        }

        // P write (wave-private rows)
        #pragma unroll
        for (int ct=0;ct<9;ct++){
            #pragma unroll
            for (int reg=0;reg<4;reg++){
                int row = w*16 + lg*4 + reg;
                *(short*)(pl + SWZ(row*320 + (ct*16+c)*2, row)) = f2b(acc[ct][reg]);
            }
        }
        #pragma unroll
        for (int reg=0;reg<4;reg++){
            int row = w*16 + lg*4 + reg;
            *(short*)(pl + SWZ(row*320 + (144+c)*2, row)) = 0;
        }
        if (c==0){
            #pragma unroll
            for (int reg=0;reg<4;reg++) psl[w*16 + lg*4 + reg] = sum[reg];
        }

        // top-k: 4 tokens in parallel (wave-private impl rows)
        {
            int tt = w*4 + lg;
            int sl = c;
            float vals[8];
            #pragma unroll
            for (int e=0;e<8;e++) vals[e] = impl[tt*128 + sl*8 + e];
            int sel[4];
            #pragma unroll
            for (int r4=0;r4<4;r4++){
                float bv = -INFINITY; int bj = 0;
                #pragma unroll
                for (int e=0;e<8;e++){
                    if (vals[e] > bv){ bv = vals[e]; bj = sl*8+e; }
                }
                #pragma unroll
                for (int o=1;o<16;o<<=1){
                    float ov = __shfl_xor(bv,o);
                    int oj = __shfl_xor(bj,o);
                    if (ov > bv || (ov==bv && oj<bj)){ bv=ov; bj=oj; }
                }
                sel[r4] = bj;
                if (sl == (bj>>3)){
                    #pragma unroll
                    for (int e=0;e<8;e++) if (e == (bj&7)) vals[e] = -INFINITY;
                }
            }
            if (sl == 0){
                int* sp = selidx + ((size_t)(hk*NN + i0 + tt))*NSEL;
                sp[0]=sel[0]; sp[1]=sel[1]; sp[2]=sel[2]; sp[3]=sel[3];
            }
        }

        f32x4 pv[4];
        #pragma unroll
        for (int ctd=0;ctd<4;ctd++) pv[ctd] = (f32x4)0.f;
        #pragma unroll
        for (int ks=0;ks<5;ks++){
            int arow = w*16 + c;
            short8v pf = *(short8v*)(pl + SWZ(arow*320 + ks*64 + lg*16, arow));
            #pragma unroll
            for (int ctd=0;ctd<4;ctd++){
                int row = ctd*16 + c;
                short8v bf = *(const short8v*)(cvhk + (size_t)row*160 + ks*32 + lg*8);
                pv[ctd] = MFMA(pf, bf, pv[ctd]);
            }
        }
        #pragma unroll
        for (int ctd=0;ctd<4;ctd++)
            #pragma unroll
            for (int reg=0;reg<4;reg++){
                int row = w*16 + lg*4 + reg;
                float inv = 1.0f/psl[row];
                int hh = hk*G + reg;
                int ii = i0 + (row>>2);
                outc[((size_t)(hh*NN + ii))*D + ctd*16 + c] = f2b(pv[ctd][reg]*inv);
            }
        return;
    }
    if (b < 1024){
        // ============ sliding-window attention (1 barrier) ============
        int idx = b - 512;
        char* aq = smem;                       // 8192
        char* pl = smem + 8192;                // 64*256 = 16384 (ends 24576)
        float* psl = (float*)(smem + 24576);   // 256
        int i0 = (idx & 31)*64, h = idx >> 5;
        int hk = h >> 2;
        int pa = i0 - 64;
        const short* khk = kb16 + (size_t)hk*NN*64;
        for (int u=0;u<2;u++){
            int cid = t + 256*u; int row = cid>>3, ch = cid&7;
            const float* src = q + ((size_t)(h*NN + i0 + row))*D + ch*8;
            f32x4 a = *(const f32x4*)src, bb2 = *(const f32x4*)(src+4);
            *(short8v*)(aq + SWZ(row*128 + ch*16, row)) = cvt8(a,bb2);
        }
        __syncthreads();

        f32x4 acc[8];
        #pragma unroll
        for (int ct=0;ct<8;ct++) acc[ct] = (f32x4)0.f;
        #pragma unroll
        for (int ks=0;ks<2;ks++){
            int arow = w*16 + c;
            short8v af = *(short8v*)(aq + SWZ(arow*128 + ks*64 + lg*16, arow));
            #pragma unroll
            for (int ct=0;ct<8;ct++){
                int j = ct*16 + c;
                int pos = pa + j; pos = pos < 0 ? 0 : pos;
                short8v bf = *(const short8v*)(khk + (size_t)pos*64 + ks*32 + lg*8);
                acc[ct] = MFMA(af, bf, acc[ct]);
            }
        }
        #pragma unroll
        for (int ct=0;ct<8;ct++){
            int j = ct*16 + c;
            #pragma unroll
            for (int reg=0;reg<4;reg++){
                int tl2 = w*16 + lg*4 + reg;
                bool vis = (j >= tl2+1) && (j <= tl2+64) && (pa + j >= 0);
                float s = acc[ct][reg]*SCALE;
                acc[ct][reg] = vis ? s : NEGV;
            }
        }
        f32x4 mx = acc[0];
        #pragma unroll
        for (int ct=1;ct<8;ct++) mx = vmax4(mx, acc[ct]);
        #pragma unroll
        for (int o=1;o<16;o<<=1) mx = vmax4(mx, shflx4(mx,o));
        f32x4 sum = (f32x4)0.f;
        #pragma unroll
        for (int ct=0;ct<8;ct++){ acc[ct] = exp4(acc[ct]-mx); sum += acc[ct]; }
        #pragma unroll
        for (int o=1;o<16;o<<=1) sum += shflx4(sum,o);

        #pragma unroll
        for (int ct=0;ct<8;ct++){
            #pragma unroll
            for (int reg=0;reg<4;reg++){
                int row = w*16 + lg*4 + reg;
                *(short*)(pl + SWZ(row*256 + (ct*16+c)*2, row)) = f2b(acc[ct][reg]);
            }
        }
        if (c==0){
            #pragma unroll
            for (int reg=0;reg<4;reg++) psl[w*16+lg*4+reg] = sum[reg];
        }

        f32x4 pv[4];
        #pragma unroll
        for (int ctd=0;ctd<4;ctd++) pv[ctd] = (f32x4)0.f;
        #pragma unroll
        for (int ks=0;ks<4;ks++){
            int arow = w*16 + c;
            short8v pf = *(short8v*)(pl + SWZ(arow*256 + ks*64 + lg*16, arow));
            int pos0 = pa + ks*32 + lg*8;
            pos0 = pos0 < 0 ? 0 : pos0;
            #pragma unroll
            for (int ctd=0;ctd<4;ctd++){
                int d = ctd*16 + c;
                short8v bf = *(const short8v*)(vTg + ((size_t)(hk*64 + d))*NN + pos0);
                pv[ctd] = MFMA(pf, bf, pv[ctd]);
            }
        }
        #pragma unroll
        for (int ctd=0;ctd<4;ctd++)
            #pragma unroll
            for (int reg=0;reg<4;reg++){
                int row = w*16 + lg*4 + reg;
                float inv = 1.0f/psl[row];
                outs[((size_t)(h*NN + i0 + row))*D + ctd*16 + c] = f2b(pv[ctd][reg]*inv);
            }
        return;
    }
    {
        // ============ gates split-K partial GEMM (B direct from cwb) ============
        int idx = b - 1024;
        char* ha = smem;
        int i0g = (idx & 31)*64, ky = idx >> 5;
        f32x4 acc[3];
        #pragma unroll
        for (int ct=0;ct<3;ct++) acc[ct] = (f32x4)0.f;
        for (int kc=0;kc<4;kc++){
            int kbase = ky*256 + kc*64;
            if (kc) __syncthreads();
            for (int u=0;u<2;u++){
                int cid = t + 256*u; int row = cid>>3, ch = cid&7;
                const float* src = hidden + (size_t)(i0g+row)*HID + kbase + ch*8;
                f32x4 a = *(const f32x4*)src, bb2 = *(const f32x4*)(src+4);
                *(short8v*)(ha + SWZ(row*128 + ch*16, row)) = cvt8(a,bb2);
            }
            __syncthreads();
            #pragma unroll
            for (int ks=0;ks<2;ks++){
                int arow = w*16 + c;
                short8v af = *(short8v*)(ha + SWZ(arow*128 + ks*64 + lg*16, arow));
                #pragma unroll
                for (int ct=0;ct<3;ct++){
                    int brow = ct*16 + c;
                    short8v bf = *(const short8v*)(cwb + (size_t)brow*HID + kbase + ks*32 + lg*8);
                    acc[ct] = MFMA(af, bf, acc[ct]);
                }
            }
        }
        #pragma unroll
        for (int ct=0;ct<3;ct++)
            #pragma unroll
            for (int reg=0;reg<4;reg++){
                int row = w*16 + lg*4 + reg;
                gpart[((size_t)ky*NN + i0g + row)*48 + ct*16 + c] = acc[ct][reg];
            }
    }
}

// ---------------------------------------------------------------------------
// K3: selected-block attention via MFMA + gate reduction (12 lanes) + gated combine.
__global__ __launch_bounds__(256) void k_selc(
    const float* __restrict__ q, const short* __restrict__ kbg, const short* __restrict__ vTg,
    const int* __restrict__ selidx,
    const short* __restrict__ outc, const short* __restrict__ outs,
    const float* __restrict__ gpart, const float* __restrict__ cbias,
    short* __restrict__ comb)
{
    __shared__ short pls[4][4*64];
    __shared__ float gsl[4][12];
    int i0 = blockIdx.x*4, hk = blockIdx.y, t = threadIdx.x;
    int wv = t>>6, lane = t&63;
    int i = i0 + wv;
    int c = lane&15, lg = lane>>4;
    int head = c & 3;

    int sel_r[4];
    #pragma unroll
    for (int nt=0;nt<4;nt++) sel_r[nt] = selidx[((size_t)(hk*NN + i))*NSEL + nt];

    short8v qa[2];
    #pragma unroll
    for (int ks=0;ks<2;ks++){
        const float* src = q + ((size_t)((hk*G + head)*NN + i))*D + ks*32 + lg*8;
        f32x4 a = *(const f32x4*)src, b = *(const f32x4*)(src+4);
        qa[ks] = cvt8(a,b);
    }

    f32x4 acc[4];
    #pragma unroll
    for (int nt=0;nt<4;nt++) acc[nt] = (f32x4)0.f;
    #pragma unroll
    for (int ks=0;ks<2;ks++){
        #pragma unroll
        for (int nt=0;nt<4;nt++){
            int pos = sel_r[nt]*CB + c;
            short8v bf = *(const short8v*)(kbg + ((size_t)(hk*NN + pos))*D + ks*32 + lg*8);
            acc[nt] = MFMA(qa[ks], bf, acc[nt]);
        }
    }
    #pragma unroll
    for (int nt=0;nt<4;nt++){
        int pos = sel_r[nt]*CB + c;
        f32x4 s = acc[nt]*SCALE;
        if (pos > i){ s[0]=NEGV; s[1]=NEGV; s[2]=NEGV; s[3]=NEGV; }
        acc[nt] = s;
    }
    f32x4 mx = acc[0];
    #pragma unroll
    for (int nt=1;nt<4;nt++) mx = vmax4(mx, acc[nt]);
    #pragma unroll
    for (int o=1;o<16;o<<=1) mx = vmax4(mx, shflx4(mx,o));
    f32x4 sum = (f32x4)0.f;
    #pragma unroll
    for (int nt=0;nt<4;nt++){ acc[nt] = exp4(acc[nt]-mx); sum += acc[nt]; }
    #pragma unroll
    for (int o=1;o<16;o<<=1) sum += shflx4(sum,o);

    if (lane < 16){
        #pragma unroll
        for (int nt=0;nt<4;nt++)
            #pragma unroll
            for (int reg=0;reg<4;reg++)
                pls[wv][reg*64 + nt*16 + lane] = f2b(acc[nt][reg]);
    }
    if (lane < 12){
        int o = hk*12 + lane;
        const float* gp0 = gpart + (size_t)i*48;
        float s = gp0[o] + gp0[(size_t)1*NN*48 + o]
                + gp0[(size_t)2*NN*48 + o] + gp0[(size_t)3*NN*48 + o] + cbias[o];
        gsl[wv][lane] = 1.0f/(1.0f+expf(-s));
    }
    __syncthreads();

    f32x4 pv[4];
    #pragma unroll
    for (int nt=0;nt<4;nt++) pv[nt] = (f32x4)0.f;
    #pragma unroll
    for (int ks=0;ks<2;ks++){
        short8v pa = *(const short8v*)(&pls[wv][head*64 + ks*32 + lg*8]);
        int sb = ks*2 + (lg>>1);
        int pos0 = sel_r[sb]*CB + (lg&1)*8;
        #pragma unroll
        for (int nt=0;nt<4;nt++){
            int d = nt*16 + c;
            short8v bf = *(const short8v*)(vTg + ((size_t)(hk*64 + d))*NN + pos0);
            pv[nt] = MFMA(pa, bf, pv[nt]);
        }
    }

    f32x4 myv = (lg==0) ? pv[0] : (lg==1) ? pv[1] : (lg==2) ? pv[2] : pv[3];
    int d = lg*16 + c;
    #pragma unroll
    for (int reg=0;reg<4;reg++){
        float g0 = gsl[wv][reg*3+0], g1 = gsl[wv][reg*3+1], g2 = gsl[wv][reg*3+2];
        size_t off = ((size_t)((hk*G+reg)*NN + i))*D + d;
        float fo = myv[reg] * (1.0f/sum[reg]);
        float val = g0*b2f(outc[off]) + g1*fo + g2*b2f(outs[off]);
        comb[(size_t)i*HID + (hk*G+reg)*64 + d] = f2b(val);
    }
}

// ---------------------------------------------------------------------------
// K4: out = comb @ wb^T (unchanged)
__global__ __launch_bounds__(256) void k_gemm(
    const short* __restrict__ A, const short* __restrict__ Bw, float* __restrict__ out)
{
    __shared__ char ab[2][64*128];
    __shared__ char bb[2][64*128];
    int m0 = blockIdx.x*64, n0 = blockIdx.y*64, t = threadIdx.x;
    int w = t>>6, lane = t&63, c = lane&15, lg = lane>>4;
    int r0 = t>>3, ch0 = t&7;
    f32x4 acc[4];
    #pragma unroll
    for (int ct=0;ct<4;ct++) acc[ct] = (f32x4)0.f;
    const short* Ap = A  + (size_t)(m0+r0)*HID + ch0*8;
    const short* Bp = Bw + (size_t)(n0+r0)*HID + ch0*8;
    short8v ra0 = *(const short8v*)(Ap);
    short8v ra1 = *(const short8v*)(Ap + 32*HID);
    short8v rb0 = *(const short8v*)(Bp);
    short8v rb1 = *(const short8v*)(Bp + 32*HID);
    for (int kc=0;kc<16;kc++){
        char* abuf = ab[kc&1];
        char* bbuf = bb[kc&1];
        *(short8v*)(abuf + SWZ(r0*128 + ch0*16, r0)) = ra0;
        *(short8v*)(abuf + SWZ((r0+32)*128 + ch0*16, r0+32)) = ra1;
        *(short8v*)(bbuf + SWZ(r0*128 + ch0*16, r0)) = rb0;
        *(short8v*)(bbuf + SWZ((r0+32)*128 + ch0*16, r0+32)) = rb1;
        __syncthreads();
        if (kc < 15){
            const short* Ap2 = Ap + (kc+1)*64;
            const short* Bp2 = Bp + (kc+1)*64;
            ra0 = *(const short8v*)(Ap2);
            ra1 = *(const short8v*)(Ap2 + 32*HID);
            rb0 = *(const short8v*)(Bp2);
            rb1 = *(const short8v*)(Bp2 + 32*HID);
        }
        #pragma unroll
        for (int ks=0;ks<2;ks++){
            int arow = w*16 + c;
            short8v af = *(short8v*)(abuf + SWZ(arow*128 + ks*64 + lg*16, arow));
            #pragma unroll
            for (int ct=0;ct<4;ct++){
                int brow = ct*16 + c;
                short8v bf = *(short8v*)(bbuf + SWZ(brow*128 + ks*64 + lg*16, brow));
                acc[ct] = MFMA(af, bf, acc[ct]);
            }
        }
    }
    #pragma unroll
    for (int ct=0;ct<4;ct++)
        #pragma unroll
        for (int reg=0;reg<4;reg++){
            int row = w*16 + lg*4 + reg;
            out[((size_t)(m0+row))*HID + n0 + ct*16 + c] = acc[ct][reg];
        }
}

// ---------------------------------------------------------------------------
extern "C" void kernel_launch(void* const* d_in, const int* in_sizes, int n_in,
                              void* d_out, int out_size, void* d_ws, size_t ws_size,
                              hipStream_t stream)
{
    const float* hidden     = (const float*)d_in[0];
    const float* q          = (const float*)d_in[1];
    const float* k          = (const float*)d_in[2];
    const float* v          = (const float*)d_in[3];
    const float* memkv      = (const float*)d_in[4];
    const float* ksc        = (const float*)d_in[5];
    const float* vsc        = (const float*)d_in[6];
    const float* combiner_w = (const float*)d_in[7];
    const float* combiner_b = (const float*)d_in[8];
    const float* combine_w  = (const float*)d_in[9];
    float* out = (float*)d_out;

    char* p = (char*)d_ws;
    short* ckb  = (short*)p; p += (size_t)HKV*144*64*2;
    short* cvtg = (short*)p; p += (size_t)HKV*64*160*2;
    short* wbg  = (short*)p; p += (size_t)HID*HID*2;
    short* cwbg = (short*)p; p += (size_t)48*HID*2;
    short* kbg  = (short*)p; p += (size_t)HKV*NN*D*2;
    short* vTg  = (short*)p; p += (size_t)HKV*64*NN*2;
    short* outc = (short*)p; p += (size_t)H*NN*D*2;
    short* outs = (short*)p; p += (size_t)H*NN*D*2;
    float* gpart= (float*)p; p += (size_t)4*NN*48*4;
    short* comb = (short*)p; p += (size_t)NN*HID*2;
    int*  selix = (int*)p;   p += (size_t)HKV*NN*NSEL*4;

    k_prep <<<848, 256, 0, stream>>>(combiner_w, k, v, memkv, ksc, vsc,
                                      cwbg, kbg, vTg, ckb, cvtg);
    k_attn <<<2176, 256, 0, stream>>>(q, ckb, cvtg, outc, selix,
                                       kbg, vTg, outs, hidden, cwbg, gpart,
                                       combine_w, wbg);
    k_selc <<<dim3(NN/4, HKV), 256, 0, stream>>>(q, kbg, vTg, selix, outc, outs,
                                                  gpart, combiner_b, comb);
    k_gemm <<<dim3(NN/64, HID/64), 256, 0, stream>>>(comb, wbg, out);
}

// Round 16
// 65.970 us; speedup vs baseline: 1.0590x; 1.0590x over previous
//
#include <hip/hip_runtime.h>
#include <hip/hip_bf16.h>
#include <math.h>

#define H    16
#define HKV  4
#define G    4
#define NN   2048
#define D    64
#define HID  1024
#define CB   16
#define W    128
#define NSEL 4
#define WIN  64
#define NEGV -1e10f
#define SCALE 0.125f

typedef __attribute__((ext_vector_type(4))) float f32x4;
typedef __attribute__((ext_vector_type(4))) short short4v;
typedef __attribute__((ext_vector_type(8))) short short8v;

__device__ inline short f2b(float x){
    __hip_bfloat16 h = __float2bfloat16(x);
    return *reinterpret_cast<short*>(&h);
}
__device__ inline float b2f(short s){
    unsigned u = ((unsigned)(unsigned short)s) << 16;
    return __builtin_bit_cast(float, u);
}
__device__ inline short8v cvt8(f32x4 a, f32x4 b){
    short8v r;
    r[0]=f2b(a[0]); r[1]=f2b(a[1]); r[2]=f2b(a[2]); r[3]=f2b(a[3]);
    r[4]=f2b(b[0]); r[5]=f2b(b[1]); r[6]=f2b(b[2]); r[7]=f2b(b[3]);
    return r;
}
#define SWZ(byte, row) ((byte) ^ (((row)&7)<<4))
#define MFMA(a,b,c) __builtin_amdgcn_mfma_f32_16x16x32_bf16(a,b,c,0,0,0)

__device__ inline float wave_sum(float x){ for(int o=32;o;o>>=1) x += __shfl_xor(x,o); return x; }

__device__ inline f32x4 vmax4(f32x4 a, f32x4 b){
    f32x4 r; r[0]=fmaxf(a[0],b[0]); r[1]=fmaxf(a[1],b[1]); r[2]=fmaxf(a[2],b[2]); r[3]=fmaxf(a[3],b[3]); return r;
}
__device__ inline f32x4 shflx4(f32x4 x, int o){
    f32x4 r; r[0]=__shfl_xor(x[0],o); r[1]=__shfl_xor(x[1],o); r[2]=__shfl_xor(x[2],o); r[3]=__shfl_xor(x[3],o); return r;
}
__device__ inline f32x4 exp4(f32x4 x){
    f32x4 r; r[0]=expf(x[0]); r[1]=expf(x[1]); r[2]=expf(x[2]); r[3]=expf(x[3]); return r;
}

// ---------------------------------------------------------------------------
// K1: fused prep (combine_w conversion lives in k_attn tail). 848 blocks.
__device__ inline void conv_seg(const float* __restrict__ src, short* __restrict__ dst,
                                int b, int t){
    size_t idx = (size_t)b*1024 + t*4;
    f32x4 a = *(const f32x4*)(src + idx);
    short4v r; r[0]=f2b(a[0]); r[1]=f2b(a[1]); r[2]=f2b(a[2]); r[3]=f2b(a[3]);
    *(short4v*)(dst + idx) = r;
}

__global__ __launch_bounds__(256) void k_prep(
    const float* __restrict__ combiner_w,
    const float* __restrict__ k, const float* __restrict__ v,
    const float* __restrict__ memkv, const float* __restrict__ ksc, const float* __restrict__ vsc,
    short* __restrict__ cwb, short* __restrict__ kb16,
    short* __restrict__ vT, short* __restrict__ ckb, short* __restrict__ cvtg)
{
    int b = blockIdx.x, t = threadIdx.x;
    if (b < 48){ conv_seg(combiner_w, cwb, b, t); return; }
    b -= 48;
    if (b < 512){ conv_seg(k, kb16, b, t); return; }
    b -= 512;
    if (b < 128){
        __shared__ float tl[64][65];
        int hk = b>>5, i0 = (b&31)*64;
        for (int u=0;u<4;u++){
            int cid = t + 256*u; int r = cid>>4, ch = cid&15;
            f32x4 a = *(const f32x4*)(v + ((size_t)(hk*NN + i0 + r))*D + ch*4);
            tl[r][ch*4+0]=a[0]; tl[r][ch*4+1]=a[1]; tl[r][ch*4+2]=a[2]; tl[r][ch*4+3]=a[3];
        }
        __syncthreads();
        int d = t>>2, qd = t&3;
        short8v p0, p1;
        #pragma unroll
        for (int e=0;e<8;e++) p0[e] = f2b(tl[qd*16+e][d]);
        #pragma unroll
        for (int e=0;e<8;e++) p1[e] = f2b(tl[qd*16+8+e][d]);
        short* dst = vT + ((size_t)(hk*64 + d))*NN + i0 + qd*16;
        *(short8v*)dst = p0;
        *(short8v*)(dst+8) = p1;
        return;
    }
    b -= 128;
    {
        int j = b;
        int hk = t>>6, d = t&63;
        if (j > 128){
            if (j < 144) ckb[((size_t)(hk*144 + j))*64 + d] = 0;
            cvtg[((size_t)(hk*64 + d))*160 + j] = 0;
            return;
        }
        float xk, xv;
        if (j==0){ xk = memkv[(0*HKV+hk)*D + d]; xv = memkv[(HKV+hk)*D + d]; }
        else {
            int jb = j-1;
            const float* kp = k + ((size_t)(hk*NN + jb*CB))*D + d;
            const float* vp = v + ((size_t)(hk*NN + jb*CB))*D + d;
            float sk=0.f, sv=0.f;
            #pragma unroll
            for (int tt=0;tt<CB;tt++){ sk += kp[tt*D]; sv += vp[tt*D]; }
            xk = sk*(1.0f/CB); xv = sv*(1.0f/CB);
            float msk = wave_sum(xk*xk)*(1.0f/D);
            float msv = wave_sum(xv*xv)*(1.0f/D);
            xk = xk*rsqrtf(msk+1e-6f)*ksc[d];
            xv = xv*rsqrtf(msv+1e-6f)*vsc[d];
        }
        ckb[((size_t)(hk*144 + j))*64 + d] = f2b(xk);
        cvtg[((size_t)(hk*64 + d))*160 + j] = f2b(xv);
    }
}

// ---------------------------------------------------------------------------
// K2: fused attention stage. cattn (0..511) + swin (512..1023) + gates split-K
// (1024..1151) + combine_w f32->bf16 conversion tail (1152..2175, fills idle CUs).
// LDS staging of B-panels retained (round-15 showed it is load-bearing).
__global__ __launch_bounds__(256, 4) void k_attn(
    const float* __restrict__ q, const short* __restrict__ ckb, const short* __restrict__ cvt_g,
    short* __restrict__ outc, int* __restrict__ selidx,
    const short* __restrict__ kb16, const short* __restrict__ vTg, short* __restrict__ outs,
    const float* __restrict__ hidden, const short* __restrict__ cwb,
    float* __restrict__ gpart,
    const float* __restrict__ combine_w, short* __restrict__ wbg)
{
    __shared__ char smem[35072];
    int b = blockIdx.x, t = threadIdx.x;
    int w = t>>6, lane = t&63, c = lane&15, lg = lane>>4;

    if (b >= 1152){ conv_seg(combine_w, wbg, b - 1152, t); return; }

    if (b < 512){
        // ================= compressed attention + importance + top-k =================
        char* aq  = smem;
        char* ckl = smem + 8192;
        char* pl  = smem;
        float* impl = (float*)(smem + 26624);
        float* psl  = (float*)(smem + 34816);
        int hk = b & 3, i0 = (b >> 2)*16;
        const short* cvhk = cvt_g + (size_t)hk*64*160;

        for (int u=0;u<2;u++){
            int cid = t + 256*u; int row = cid>>3, ch = cid&7;
            const float* src = q + ((size_t)((hk*G + (row&3))*NN + i0 + (row>>2)))*D + ch*8;
            f32x4 a = *(const f32x4*)src, bb2 = *(const f32x4*)(src+4);
            *(short8v*)(aq + SWZ(row*128 + ch*16, row)) = cvt8(a,bb2);
        }
        for (int u=0;u<5;u++){
            int cid = t + 256*u;
            if (cid < 1152){
                int row = cid>>3, ch = cid&7;
                const short* src = ckb + ((size_t)(hk*144 + row))*64 + ch*8;
                *(short8v*)(ckl + SWZ(row*128 + ch*16, row)) = *(const short8v*)src;
            }
        }
        __syncthreads();

        f32x4 acc[9];
        #pragma unroll
        for (int ct=0;ct<9;ct++) acc[ct] = (f32x4)0.f;
        #pragma unroll
        for (int ks=0;ks<2;ks++){
            int arow = w*16 + c;
            short8v af = *(short8v*)(aq + SWZ(arow*128 + ks*64 + lg*16, arow));
            #pragma unroll
            for (int ct=0;ct<9;ct++){
                int row = ct*16 + c;
                short8v bf = *(short8v*)(ckl + SWZ(row*128 + ks*64 + lg*16, row));
                acc[ct] = MFMA(af, bf, acc[ct]);
            }
        }

        f32x4 sum;
        {
            int tloc = w*4 + lg;
            int ii = i0 + tloc;
            #pragma unroll
            for (int ct=0;ct<9;ct++){
                int j = ct*16 + c;
                bool vis = (j==0) || (j<=128 && j*16 <= ii);
                f32x4 s = acc[ct]*SCALE;
                if (!vis){ s[0]=NEGV; s[1]=NEGV; s[2]=NEGV; s[3]=NEGV; }
                acc[ct] = s;
            }
            #pragma unroll
            for (int ct=0;ct<9;ct++){
                int j = ct*16 + c;
                if (j>=1 && j<=128){
                    f32x4 s = acc[ct];
                    impl[tloc*128 + (j-1)] = 0.25f*(s[0]+s[1]+s[2]+s[3]);
                }
            }
            f32x4 mx = acc[0];
            #pragma unroll
            for (int ct=1;ct<9;ct++) mx = vmax4(mx, acc[ct]);
            #pragma unroll
            for (int o=1;o<16;o<<=1) mx = vmax4(mx, shflx4(mx,o));
            sum = (f32x4)0.f;
            #pragma unroll
            for (int ct=0;ct<9;ct++){ acc[ct] = exp4(acc[ct]-mx); sum += acc[ct]; }
            #pragma unroll
            for (int o=1;o<16;o<<=1) sum += shflx4(sum,o);
        }
        __syncthreads();

        #pragma unroll
        for (int ct=0;ct<9;ct++){
            #pragma unroll
            for (int reg=0;reg<4;reg++){
                int row = w*16 + lg*4 + reg;
                *(short*)(pl + SWZ(row*320 + (ct*16+c)*2, row)) = f2b(acc[ct][reg]);
            }
        }
        #pragma unroll
        for (int reg=0;reg<4;reg++){
            int row = w*16 + lg*4 + reg;
            *(short*)(pl + SWZ(row*320 + (144+c)*2, row)) = 0;
        }
        if (c==0){
            #pragma unroll
            for (int reg=0;reg<4;reg++) psl[w*16 + lg*4 + reg] = sum[reg];
        }
        __syncthreads();

        // top-k: 4 tokens in parallel (one per 16-lane group)
        {
            int tt = w*4 + lg;
            int sl = c;
            float vals[8];
            #pragma unroll
            for (int e=0;e<8;e++) vals[e] = impl[tt*128 + sl*8 + e];
            int sel[4];
            #pragma unroll
            for (int r4=0;r4<4;r4++){
                float bv = -INFINITY; int bj = 0;
                #pragma unroll
                for (int e=0;e<8;e++){
                    if (vals[e] > bv){ bv = vals[e]; bj = sl*8+e; }
                }
                #pragma unroll
                for (int o=1;o<16;o<<=1){
                    float ov = __shfl_xor(bv,o);
                    int oj = __shfl_xor(bj,o);
                    if (ov > bv || (ov==bv && oj<bj)){ bv=ov; bj=oj; }
                }
                sel[r4] = bj;
                if (sl == (bj>>3)){
                    #pragma unroll
                    for (int e=0;e<8;e++) if (e == (bj&7)) vals[e] = -INFINITY;
                }
            }
            if (sl == 0){
                int* sp = selidx + ((size_t)(hk*NN + i0 + tt))*NSEL;
                sp[0]=sel[0]; sp[1]=sel[1]; sp[2]=sel[2]; sp[3]=sel[3];
            }
        }

        f32x4 pv[4];
        #pragma unroll
        for (int ctd=0;ctd<4;ctd++) pv[ctd] = (f32x4)0.f;
        #pragma unroll
        for (int ks=0;ks<5;ks++){
            int arow = w*16 + c;
            short8v pf = *(short8v*)(pl + SWZ(arow*320 + ks*64 + lg*16, arow));
            #pragma unroll
            for (int ctd=0;ctd<4;ctd++){
                int row = ctd*16 + c;
                short8v bf = *(const short8v*)(cvhk + (size_t)row*160 + ks*32 + lg*8);
                pv[ctd] = MFMA(pf, bf, pv[ctd]);
            }
        }
        #pragma unroll
        for (int ctd=0;ctd<4;ctd++)
            #pragma unroll
            for (int reg=0;reg<4;reg++){
                int row = w*16 + lg*4 + reg;
                float inv = 1.0f/psl[row];
                int hh = hk*G + reg;
                int ii = i0 + (row>>2);
                outc[((size_t)(hh*NN + ii))*D + ctd*16 + c] = f2b(pv[ctd][reg]*inv);
            }
        return;
    }
    if (b < 1024){
        // ================= sliding-window attention =================
        int idx = b - 512;
        char* aq = smem;
        char* kb = smem + 8192;
        float* psl = (float*)(smem + 24576);
        char* pl = kb;
        int i0 = (idx & 31)*64, h = idx >> 5;
        int hk = h >> 2;
        int pa = i0 - 64;
        for (int u=0;u<2;u++){
            int cid = t + 256*u; int row = cid>>3, ch = cid&7;
            const float* src = q + ((size_t)(h*NN + i0 + row))*D + ch*8;
            f32x4 a = *(const f32x4*)src, bb2 = *(const f32x4*)(src+4);
            *(short8v*)(aq + SWZ(row*128 + ch*16, row)) = cvt8(a,bb2);
        }
        for (int u=0;u<4;u++){
            int cid = t + 256*u; int row = cid>>3, ch = cid&7;
            int pos = pa + row; pos = pos < 0 ? 0 : pos;
            *(short8v*)(kb + SWZ(row*128 + ch*16, row)) =
                *(const short8v*)(kb16 + ((size_t)(hk*NN + pos))*D + ch*8);
        }
        __syncthreads();
        f32x4 acc[8];
        #pragma unroll
        for (int ct=0;ct<8;ct++) acc[ct] = (f32x4)0.f;
        #pragma unroll
        for (int ks=0;ks<2;ks++){
            int arow = w*16 + c;
            short8v af = *(short8v*)(aq + SWZ(arow*128 + ks*64 + lg*16, arow));
            #pragma unroll
            for (int ct=0;ct<8;ct++){
                int brow = ct*16 + c;
                short8v bf = *(short8v*)(kb + SWZ(brow*128 + ks*64 + lg*16, brow));
                acc[ct] = MFMA(af, bf, acc[ct]);
            }
        }
        #pragma unroll
        for (int ct=0;ct<8;ct++){
            int j = ct*16 + c;
            #pragma unroll
            for (int reg=0;reg<4;reg++){
                int tl2 = w*16 + lg*4 + reg;
                bool vis = (j >= tl2+1) && (j <= tl2+64) && (pa + j >= 0);
                float s = acc[ct][reg]*SCALE;
                acc[ct][reg] = vis ? s : NEGV;
            }
        }
        f32x4 mx = acc[0];
        #pragma unroll
        for (int ct=1;ct<8;ct++) mx = vmax4(mx, acc[ct]);
        #pragma unroll
        for (int o=1;o<16;o<<=1) mx = vmax4(mx, shflx4(mx,o));
        f32x4 sum = (f32x4)0.f;
        #pragma unroll
        for (int ct=0;ct<8;ct++){ acc[ct] = exp4(acc[ct]-mx); sum += acc[ct]; }
        #pragma unroll
        for (int o=1;o<16;o<<=1) sum += shflx4(sum,o);
        __syncthreads();
        #pragma unroll
        for (int ct=0;ct<8;ct++){
            #pragma unroll
            for (int reg=0;reg<4;reg++){
                int row = w*16 + lg*4 + reg;
                *(short*)(pl + SWZ(row*256 + (ct*16+c)*2, row)) = f2b(acc[ct][reg]);
            }
        }
        if (c==0){
            #pragma unroll
            for (int reg=0;reg<4;reg++) psl[w*16+lg*4+reg] = sum[reg];
        }
        __syncthreads();
        f32x4 pv[4];
        #pragma unroll
        for (int ctd=0;ctd<4;ctd++) pv[ctd] = (f32x4)0.f;
        #pragma unroll
        for (int ks=0;ks<4;ks++){
            int arow = w*16 + c;
            short8v pf = *(short8v*)(pl + SWZ(arow*256 + ks*64 + lg*16, arow));
            int pos0 = pa + ks*32 + lg*8;
            pos0 = pos0 < 0 ? 0 : pos0;
            #pragma unroll
            for (int ctd=0;ctd<4;ctd++){
                int d = ctd*16 + c;
                short8v bf = *(const short8v*)(vTg + ((size_t)(hk*64 + d))*NN + pos0);
                pv[ctd] = MFMA(pf, bf, pv[ctd]);
            }
        }
        #pragma unroll
        for (int ctd=0;ctd<4;ctd++)
            #pragma unroll
            for (int reg=0;reg<4;reg++){
                int row = w*16 + lg*4 + reg;
                float inv = 1.0f/psl[row];
                outs[((size_t)(h*NN + i0 + row))*D + ctd*16 + c] = f2b(pv[ctd][reg]*inv);
            }
        return;
    }
    {
        // ================= gates split-K partial GEMM =================
        int idx = b - 1024;
        char* ha = smem;
        char* bl = smem + 8192;
        int i0g = (idx & 31)*64, ky = idx >> 5;
        f32x4 acc[3];
        #pragma unroll
        for (int ct=0;ct<3;ct++) acc[ct] = (f32x4)0.f;
        for (int kc=0;kc<4;kc++){
            int kbase = ky*256 + kc*64;
            if (kc) __syncthreads();
            for (int u=0;u<2;u++){
                int cid = t + 256*u; int row = cid>>3, ch = cid&7;
                const float* src = hidden + (size_t)(i0g+row)*HID + kbase + ch*8;
                f32x4 a = *(const f32x4*)src, bb2 = *(const f32x4*)(src+4);
                *(short8v*)(ha + SWZ(row*128 + ch*16, row)) = cvt8(a,bb2);
            }
            for (int u=0;u<2;u++){
                int cid = t + 256*u;
                if (cid < 384){
                    int row = cid>>3, ch = cid&7;
                    *(short8v*)(bl + SWZ(row*128 + ch*16, row)) =
                        *(const short8v*)(cwb + (size_t)row*HID + kbase + ch*8);
                }
            }
            __syncthreads();
            #pragma unroll
            for (int ks=0;ks<2;ks++){
                int arow = w*16 + c;
                short8v af = *(short8v*)(ha + SWZ(arow*128 + ks*64 + lg*16, arow));
                #pragma unroll
                for (int ct=0;ct<3;ct++){
                    int brow = ct*16 + c;
                    short8v bf = *(short8v*)(bl + SWZ(brow*128 + ks*64 + lg*16, brow));
                    acc[ct] = MFMA(af, bf, acc[ct]);
                }
            }
        }
        #pragma unroll
        for (int ct=0;ct<3;ct++)
            #pragma unroll
            for (int reg=0;reg<4;reg++){
                int row = w*16 + lg*4 + reg;
                gpart[((size_t)ky*NN + i0g + row)*48 + ct*16 + c] = acc[ct][reg];
            }
    }
}

// ---------------------------------------------------------------------------
// K3: selected-block attention via MFMA + gate reduction (12 lanes) + gated combine.
__global__ __launch_bounds__(256) void k_selc(
    const float* __restrict__ q, const short* __restrict__ kbg, const short* __restrict__ vTg,
    const int* __restrict__ selidx,
    const short* __restrict__ outc, const short* __restrict__ outs,
    const float* __restrict__ gpart, const float* __restrict__ cbias,
    short* __restrict__ comb)
{
    __shared__ short pls[4][4*64];
    __shared__ float gsl[4][12];
    int i0 = blockIdx.x*4, hk = blockIdx.y, t = threadIdx.x;
    int wv = t>>6, lane = t&63;
    int i = i0 + wv;
    int c = lane&15, lg = lane>>4;
    int head = c & 3;

    int sel_r[4];
    #pragma unroll
    for (int nt=0;nt<4;nt++) sel_r[nt] = selidx[((size_t)(hk*NN + i))*NSEL + nt];

    short8v qa[2];
    #pragma unroll
    for (int ks=0;ks<2;ks++){
        const float* src = q + ((size_t)((hk*G + head)*NN + i))*D + ks*32 + lg*8;
        f32x4 a = *(const f32x4*)src, b = *(const f32x4*)(src+4);
        qa[ks] = cvt8(a,b);
    }

    f32x4 acc[4];
    #pragma unroll
    for (int nt=0;nt<4;nt++) acc[nt] = (f32x4)0.f;
    #pragma unroll
    for (int ks=0;ks<2;ks++){
        #pragma unroll
        for (int nt=0;nt<4;nt++){
            int pos = sel_r[nt]*CB + c;
            short8v bf = *(const short8v*)(kbg + ((size_t)(hk*NN + pos))*D + ks*32 + lg*8);
            acc[nt] = MFMA(qa[ks], bf, acc[nt]);
        }
    }
    #pragma unroll
    for (int nt=0;nt<4;nt++){
        int pos = sel_r[nt]*CB + c;
        f32x4 s = acc[nt]*SCALE;
        if (pos > i){ s[0]=NEGV; s[1]=NEGV; s[2]=NEGV; s[3]=NEGV; }
        acc[nt] = s;
    }
    f32x4 mx = acc[0];
    #pragma unroll
    for (int nt=1;nt<4;nt++) mx = vmax4(mx, acc[nt]);
    #pragma unroll
    for (int o=1;o<16;o<<=1) mx = vmax4(mx, shflx4(mx,o));
    f32x4 sum = (f32x4)0.f;
    #pragma unroll
    for (int nt=0;nt<4;nt++){ acc[nt] = exp4(acc[nt]-mx); sum += acc[nt]; }
    #pragma unroll
    for (int o=1;o<16;o<<=1) sum += shflx4(sum,o);

    if (lane < 16){
        #pragma unroll
        for (int nt=0;nt<4;nt++)
            #pragma unroll
            for (int reg=0;reg<4;reg++)
                pls[wv][reg*64 + nt*16 + lane] = f2b(acc[nt][reg]);
    }
    if (lane < 12){
        int o = hk*12 + lane;
        const float* gp0 = gpart + (size_t)i*48;
        float s = gp0[o] + gp0[(size_t)1*NN*48 + o]
                + gp0[(size_t)2*NN*48 + o] + gp0[(size_t)3*NN*48 + o] + cbias[o];
        gsl[wv][lane] = 1.0f/(1.0f+expf(-s));
    }
    __syncthreads();

    f32x4 pv[4];
    #pragma unroll
    for (int nt=0;nt<4;nt++) pv[nt] = (f32x4)0.f;
    #pragma unroll
    for (int ks=0;ks<2;ks++){
        short8v pa = *(const short8v*)(&pls[wv][head*64 + ks*32 + lg*8]);
        int sb = ks*2 + (lg>>1);
        int pos0 = sel_r[sb]*CB + (lg&1)*8;
        #pragma unroll
        for (int nt=0;nt<4;nt++){
            int d = nt*16 + c;
            short8v bf = *(const short8v*)(vTg + ((size_t)(hk*64 + d))*NN + pos0);
            pv[nt] = MFMA(pa, bf, pv[nt]);
        }
    }

    f32x4 myv = (lg==0) ? pv[0] : (lg==1) ? pv[1] : (lg==2) ? pv[2] : pv[3];
    int d = lg*16 + c;
    #pragma unroll
    for (int reg=0;reg<4;reg++){
        float g0 = gsl[wv][reg*3+0], g1 = gsl[wv][reg*3+1], g2 = gsl[wv][reg*3+2];
        size_t off = ((size_t)((hk*G+reg)*NN + i))*D + d;
        float fo = myv[reg] * (1.0f/sum[reg]);
        float val = g0*b2f(outc[off]) + g1*fo + g2*b2f(outs[off]);
        comb[(size_t)i*HID + (hk*G+reg)*64 + d] = f2b(val);
    }
}

// ---------------------------------------------------------------------------
// K4: out = comb @ wb^T (unchanged)
__global__ __launch_bounds__(256) void k_gemm(
    const short* __restrict__ A, const short* __restrict__ Bw, float* __restrict__ out)
{
    __shared__ char ab[2][64*128];
    __shared__ char bb[2][64*128];
    int m0 = blockIdx.x*64, n0 = blockIdx.y*64, t = threadIdx.x;
    int w = t>>6, lane = t&63, c = lane&15, lg = lane>>4;
    int r0 = t>>3, ch0 = t&7;
    f32x4 acc[4];
    #pragma unroll
    for (int ct=0;ct<4;ct++) acc[ct] = (f32x4)0.f;
    const short* Ap = A  + (size_t)(m0+r0)*HID + ch0*8;
    const short* Bp = Bw + (size_t)(n0+r0)*HID + ch0*8;
    short8v ra0 = *(const short8v*)(Ap);
    short8v ra1 = *(const short8v*)(Ap + 32*HID);
    short8v rb0 = *(const short8v*)(Bp);
    short8v rb1 = *(const short8v*)(Bp + 32*HID);
    for (int kc=0;kc<16;kc++){
        char* abuf = ab[kc&1];
        char* bbuf = bb[kc&1];
        *(short8v*)(abuf + SWZ(r0*128 + ch0*16, r0)) = ra0;
        *(short8v*)(abuf + SWZ((r0+32)*128 + ch0*16, r0+32)) = ra1;
        *(short8v*)(bbuf + SWZ(r0*128 + ch0*16, r0)) = rb0;
        *(short8v*)(bbuf + SWZ((r0+32)*128 + ch0*16, r0+32)) = rb1;
        __syncthreads();
        if (kc < 15){
            const short* Ap2 = Ap + (kc+1)*64;
            const short* Bp2 = Bp + (kc+1)*64;
            ra0 = *(const short8v*)(Ap2);
            ra1 = *(const short8v*)(Ap2 + 32*HID);
            rb0 = *(const short8v*)(Bp2);
            rb1 = *(const short8v*)(Bp2 + 32*HID);
        }
        #pragma unroll
        for (int ks=0;ks<2;ks++){
            int arow = w*16 + c;
            short8v af = *(short8v*)(abuf + SWZ(arow*128 + ks*64 + lg*16, arow));
            #pragma unroll
            for (int ct=0;ct<4;ct++){
                int brow = ct*16 + c;
                short8v bf = *(short8v*)(bbuf + SWZ(brow*128 + ks*64 + lg*16, brow));
                acc[ct] = MFMA(af, bf, acc[ct]);
            }
        }
    }
    #pragma unroll
    for (int ct=0;ct<4;ct++)
        #pragma unroll
        for (int reg=0;reg<4;reg++){
            int row = w*16 + lg*4 + reg;
            out[((size_t)(m0+row))*HID + n0 + ct*16 + c] = acc[ct][reg];
        }
}

// ---------------------------------------------------------------------------
extern "C" void kernel_launch(void* const* d_in, const int* in_sizes, int n_in,
                              void* d_out, int out_size, void* d_ws, size_t ws_size,
                              hipStream_t stream)
{
    const float* hidden     = (const float*)d_in[0];
    const float* q          = (const float*)d_in[1];
    const float* k          = (const float*)d_in[2];
    const float* v          = (const float*)d_in[3];
    const float* memkv      = (const float*)d_in[4];
    const float* ksc        = (const float*)d_in[5];
    const float* vsc        = (const float*)d_in[6];
    const float* combiner_w = (const float*)d_in[7];
    const float* combiner_b = (const float*)d_in[8];
    const float* combine_w  = (const float*)d_in[9];
    float* out = (float*)d_out;

    char* p = (char*)d_ws;
    short* ckb  = (short*)p; p += (size_t)HKV*144*64*2;
    short* cvtg = (short*)p; p += (size_t)HKV*64*160*2;
    short* wbg  = (short*)p; p += (size_t)HID*HID*2;
    short* cwbg = (short*)p; p += (size_t)48*HID*2;
    short* kbg  = (short*)p; p += (size_t)HKV*NN*D*2;
    short* vTg  = (short*)p; p += (size_t)HKV*64*NN*2;
    short* outc = (short*)p; p += (size_t)H*NN*D*2;
    short* outs = (short*)p; p += (size_t)H*NN*D*2;
    float* gpart= (float*)p; p += (size_t)4*NN*48*4;
    short* comb = (short*)p; p += (size_t)NN*HID*2;
    int*  selix = (int*)p;   p += (size_t)HKV*NN*NSEL*4;

    k_prep <<<848, 256, 0, stream>>>(combiner_w, k, v, memkv, ksc, vsc,
                                      cwbg, kbg, vTg, ckb, cvtg);
    k_attn <<<2176, 256, 0, stream>>>(q, ckb, cvtg, outc, selix,
                                       kbg, vTg, outs, hidden, cwbg, gpart,
                                       combine_w, wbg);
    k_selc <<<dim3(NN/4, HKV), 256, 0, stream>>>(q, kbg, vTg, selix, outc, outs,
                                                  gpart, combiner_b, comb);
    k_gemm <<<dim3(NN/64, HID/64), 256, 0, stream>>>(comb, wbg, out);
}

// Round 17
// 62.532 us; speedup vs baseline: 1.1172x; 1.0550x over previous
//
#include <hip/hip_runtime.h>
#include <hip/hip_bf16.h>
#include <math.h>

#define H    16
#define HKV  4
#define G    4
#define NN   2048
#define D    64
#define HID  1024
#define CB   16
#define W    128
#define NSEL 4
#define WIN  64
#define NEGV -1e10f
#define SCALE 0.125f

typedef __attribute__((ext_vector_type(4))) float f32x4;
typedef __attribute__((ext_vector_type(4))) short short4v;
typedef __attribute__((ext_vector_type(8))) short short8v;

__device__ inline short f2b(float x){
    __hip_bfloat16 h = __float2bfloat16(x);
    return *reinterpret_cast<short*>(&h);
}
__device__ inline float b2f(short s){
    unsigned u = ((unsigned)(unsigned short)s) << 16;
    return __builtin_bit_cast(float, u);
}
__device__ inline short8v cvt8(f32x4 a, f32x4 b){
    short8v r;
    r[0]=f2b(a[0]); r[1]=f2b(a[1]); r[2]=f2b(a[2]); r[3]=f2b(a[3]);
    r[4]=f2b(b[0]); r[5]=f2b(b[1]); r[6]=f2b(b[2]); r[7]=f2b(b[3]);
    return r;
}
#define SWZ(byte, row) ((byte) ^ (((row)&7)<<4))
#define MFMA(a,b,c) __builtin_amdgcn_mfma_f32_16x16x32_bf16(a,b,c,0,0,0)

__device__ inline float wave_sum(float x){ for(int o=32;o;o>>=1) x += __shfl_xor(x,o); return x; }

__device__ inline f32x4 vmax4(f32x4 a, f32x4 b){
    f32x4 r; r[0]=fmaxf(a[0],b[0]); r[1]=fmaxf(a[1],b[1]); r[2]=fmaxf(a[2],b[2]); r[3]=fmaxf(a[3],b[3]); return r;
}
__device__ inline f32x4 shflx4(f32x4 x, int o){
    f32x4 r; r[0]=__shfl_xor(x[0],o); r[1]=__shfl_xor(x[1],o); r[2]=__shfl_xor(x[2],o); r[3]=__shfl_xor(x[3],o); return r;
}
__device__ inline f32x4 exp4(f32x4 x){
    f32x4 r; r[0]=expf(x[0]); r[1]=expf(x[1]); r[2]=expf(x[2]); r[3]=expf(x[3]); return r;
}

// ---------------------------------------------------------------------------
// K1: fused prep (combine_w conversion lives in k_attn tail). 848 blocks.
__device__ inline void conv_seg(const float* __restrict__ src, short* __restrict__ dst,
                                int b, int t){
    size_t idx = (size_t)b*1024 + t*4;
    f32x4 a = *(const f32x4*)(src + idx);
    short4v r; r[0]=f2b(a[0]); r[1]=f2b(a[1]); r[2]=f2b(a[2]); r[3]=f2b(a[3]);
    *(short4v*)(dst + idx) = r;
}

__global__ __launch_bounds__(256) void k_prep(
    const float* __restrict__ combiner_w,
    const float* __restrict__ k, const float* __restrict__ v,
    const float* __restrict__ memkv, const float* __restrict__ ksc, const float* __restrict__ vsc,
    short* __restrict__ cwb, short* __restrict__ kb16,
    short* __restrict__ vT, short* __restrict__ ckb, short* __restrict__ cvtg)
{
    int b = blockIdx.x, t = threadIdx.x;
    if (b < 48){ conv_seg(combiner_w, cwb, b, t); return; }
    b -= 48;
    if (b < 512){ conv_seg(k, kb16, b, t); return; }
    b -= 512;
    if (b < 128){
        __shared__ float tl[64][65];
        int hk = b>>5, i0 = (b&31)*64;
        for (int u=0;u<4;u++){
            int cid = t + 256*u; int r = cid>>4, ch = cid&15;
            f32x4 a = *(const f32x4*)(v + ((size_t)(hk*NN + i0 + r))*D + ch*4);
            tl[r][ch*4+0]=a[0]; tl[r][ch*4+1]=a[1]; tl[r][ch*4+2]=a[2]; tl[r][ch*4+3]=a[3];
        }
        __syncthreads();
        int d = t>>2, qd = t&3;
        short8v p0, p1;
        #pragma unroll
        for (int e=0;e<8;e++) p0[e] = f2b(tl[qd*16+e][d]);
        #pragma unroll
        for (int e=0;e<8;e++) p1[e] = f2b(tl[qd*16+8+e][d]);
        short* dst = vT + ((size_t)(hk*64 + d))*NN + i0 + qd*16;
        *(short8v*)dst = p0;
        *(short8v*)(dst+8) = p1;
        return;
    }
    b -= 128;
    {
        int j = b;
        int hk = t>>6, d = t&63;
        if (j > 128){
            if (j < 144) ckb[((size_t)(hk*144 + j))*64 + d] = 0;
            cvtg[((size_t)(hk*64 + d))*160 + j] = 0;
            return;
        }
        float xk, xv;
        if (j==0){ xk = memkv[(0*HKV+hk)*D + d]; xv = memkv[(HKV+hk)*D + d]; }
        else {
            int jb = j-1;
            const float* kp = k + ((size_t)(hk*NN + jb*CB))*D + d;
            const float* vp = v + ((size_t)(hk*NN + jb*CB))*D + d;
            float sk=0.f, sv=0.f;
            #pragma unroll
            for (int tt=0;tt<CB;tt++){ sk += kp[tt*D]; sv += vp[tt*D]; }
            xk = sk*(1.0f/CB); xv = sv*(1.0f/CB);
            float msk = wave_sum(xk*xk)*(1.0f/D);
            float msv = wave_sum(xv*xv)*(1.0f/D);
            xk = xk*rsqrtf(msk+1e-6f)*ksc[d];
            xv = xv*rsqrtf(msv+1e-6f)*vsc[d];
        }
        ckb[((size_t)(hk*144 + j))*64 + d] = f2b(xk);
        cvtg[((size_t)(hk*64 + d))*160 + j] = f2b(xv);
    }
}

// ---------------------------------------------------------------------------
// K2: fused attention stage. cattn (0..511) + swin (512..1023) + gates split-K
// (1024..1151) + combine_w conversion tail (1152..2175).
// LDS diet: 28928 B static (impl relocated into dead ckl region after barrier;
// imp values carried in registers across the barrier) -> 5 blocks/CU.
__global__ __launch_bounds__(256, 5) void k_attn(
    const float* __restrict__ q, const short* __restrict__ ckb, const short* __restrict__ cvt_g,
    short* __restrict__ outc, int* __restrict__ selidx,
    const short* __restrict__ kb16, const short* __restrict__ vTg, short* __restrict__ outs,
    const float* __restrict__ hidden, const short* __restrict__ cwb,
    float* __restrict__ gpart,
    const float* __restrict__ combine_w, short* __restrict__ wbg)
{
    __shared__ char smem[28928];
    int b = blockIdx.x, t = threadIdx.x;
    int w = t>>6, lane = t&63, c = lane&15, lg = lane>>4;

    if (b >= 1152){ conv_seg(combine_w, wbg, b - 1152, t); return; }

    if (b < 512){
        // ================= compressed attention + importance + top-k =================
        char* aq  = smem;                      // staging: 8192
        char* ckl = smem + 8192;               // staging: 18432 (ends 26624)
        char* pl  = smem;                      // post-barrier: 20480
        float* impl = (float*)(smem + 20480);  // post-barrier: 8192 (ends 28672)
        float* psl  = (float*)(smem + 28672);  // post-barrier: 256 (ends 28928)
        int hk = b & 3, i0 = (b >> 2)*16;
        const short* cvhk = cvt_g + (size_t)hk*64*160;

        for (int u=0;u<2;u++){
            int cid = t + 256*u; int row = cid>>3, ch = cid&7;
            const float* src = q + ((size_t)((hk*G + (row&3))*NN + i0 + (row>>2)))*D + ch*8;
            f32x4 a = *(const f32x4*)src, bb2 = *(const f32x4*)(src+4);
            *(short8v*)(aq + SWZ(row*128 + ch*16, row)) = cvt8(a,bb2);
        }
        for (int u=0;u<5;u++){
            int cid = t + 256*u;
            if (cid < 1152){
                int row = cid>>3, ch = cid&7;
                const short* src = ckb + ((size_t)(hk*144 + row))*64 + ch*8;
                *(short8v*)(ckl + SWZ(row*128 + ch*16, row)) = *(const short8v*)src;
            }
        }
        __syncthreads();

        f32x4 acc[9];
        #pragma unroll
        for (int ct=0;ct<9;ct++) acc[ct] = (f32x4)0.f;
        #pragma unroll
        for (int ks=0;ks<2;ks++){
            int arow = w*16 + c;
            short8v af = *(short8v*)(aq + SWZ(arow*128 + ks*64 + lg*16, arow));
            #pragma unroll
            for (int ct=0;ct<9;ct++){
                int row = ct*16 + c;
                short8v bf = *(short8v*)(ckl + SWZ(row*128 + ks*64 + lg*16, row));
                acc[ct] = MFMA(af, bf, acc[ct]);
            }
        }

        // mask + scale; importance kept in REGISTERS until after the barrier
        f32x4 sum;
        float imp9[9];
        int tloc = w*4 + lg;
        {
            int ii = i0 + tloc;
            #pragma unroll
            for (int ct=0;ct<9;ct++){
                int j = ct*16 + c;
                bool vis = (j==0) || (j<=128 && j*16 <= ii);
                f32x4 s = acc[ct]*SCALE;
                if (!vis){ s[0]=NEGV; s[1]=NEGV; s[2]=NEGV; s[3]=NEGV; }
                acc[ct] = s;
            }
            #pragma unroll
            for (int ct=0;ct<9;ct++){
                f32x4 s = acc[ct];
                imp9[ct] = 0.25f*(s[0]+s[1]+s[2]+s[3]);
            }
            f32x4 mx = acc[0];
            #pragma unroll
            for (int ct=1;ct<9;ct++) mx = vmax4(mx, acc[ct]);
            #pragma unroll
            for (int o=1;o<16;o<<=1) mx = vmax4(mx, shflx4(mx,o));
            sum = (f32x4)0.f;
            #pragma unroll
            for (int ct=0;ct<9;ct++){ acc[ct] = exp4(acc[ct]-mx); sum += acc[ct]; }
            #pragma unroll
            for (int o=1;o<16;o<<=1) sum += shflx4(sum,o);
        }
        __syncthreads();   // all QK reads of aq/ckl done; region becomes pl/impl/psl

        #pragma unroll
        for (int ct=0;ct<9;ct++){
            #pragma unroll
            for (int reg=0;reg<4;reg++){
                int row = w*16 + lg*4 + reg;
                *(short*)(pl + SWZ(row*320 + (ct*16+c)*2, row)) = f2b(acc[ct][reg]);
            }
        }
        #pragma unroll
        for (int reg=0;reg<4;reg++){
            int row = w*16 + lg*4 + reg;
            *(short*)(pl + SWZ(row*320 + (144+c)*2, row)) = 0;
        }
        #pragma unroll
        for (int ct=0;ct<9;ct++){
            int j = ct*16 + c;
            if (j>=1 && j<=128) impl[tloc*128 + (j-1)] = imp9[ct];
        }
        if (c==0){
            #pragma unroll
            for (int reg=0;reg<4;reg++) psl[w*16 + lg*4 + reg] = sum[reg];
        }
        __syncthreads();

        // top-k: 4 tokens in parallel (one per 16-lane group)
        {
            int tt = w*4 + lg;
            int sl = c;
            float vals[8];
            #pragma unroll
            for (int e=0;e<8;e++) vals[e] = impl[tt*128 + sl*8 + e];
            int sel[4];
            #pragma unroll
            for (int r4=0;r4<4;r4++){
                float bv = -INFINITY; int bj = 0;
                #pragma unroll
                for (int e=0;e<8;e++){
                    if (vals[e] > bv){ bv = vals[e]; bj = sl*8+e; }
                }
                #pragma unroll
                for (int o=1;o<16;o<<=1){
                    float ov = __shfl_xor(bv,o);
                    int oj = __shfl_xor(bj,o);
                    if (ov > bv || (ov==bv && oj<bj)){ bv=ov; bj=oj; }
                }
                sel[r4] = bj;
                if (sl == (bj>>3)){
                    #pragma unroll
                    for (int e=0;e<8;e++) if (e == (bj&7)) vals[e] = -INFINITY;
                }
            }
            if (sl == 0){
                int* sp = selidx + ((size_t)(hk*NN + i0 + tt))*NSEL;
                sp[0]=sel[0]; sp[1]=sel[1]; sp[2]=sel[2]; sp[3]=sel[3];
            }
        }

        f32x4 pv[4];
        #pragma unroll
        for (int ctd=0;ctd<4;ctd++) pv[ctd] = (f32x4)0.f;
        #pragma unroll
        for (int ks=0;ks<5;ks++){
            int arow = w*16 + c;
            short8v pf = *(short8v*)(pl + SWZ(arow*320 + ks*64 + lg*16, arow));
            #pragma unroll
            for (int ctd=0;ctd<4;ctd++){
                int row = ctd*16 + c;
                short8v bf = *(const short8v*)(cvhk + (size_t)row*160 + ks*32 + lg*8);
                pv[ctd] = MFMA(pf, bf, pv[ctd]);
            }
        }
        #pragma unroll
        for (int ctd=0;ctd<4;ctd++)
            #pragma unroll
            for (int reg=0;reg<4;reg++){
                int row = w*16 + lg*4 + reg;
                float inv = 1.0f/psl[row];
                int hh = hk*G + reg;
                int ii = i0 + (row>>2);
                outc[((size_t)(hh*NN + ii))*D + ctd*16 + c] = f2b(pv[ctd][reg]*inv);
            }
        return;
    }
    if (b < 1024){
        // ================= sliding-window attention =================
        int idx = b - 512;
        char* aq = smem;
        char* kb = smem + 8192;
        float* psl = (float*)(smem + 24576);
        char* pl = kb;
        int i0 = (idx & 31)*64, h = idx >> 5;
        int hk = h >> 2;
        int pa = i0 - 64;
        for (int u=0;u<2;u++){
            int cid = t + 256*u; int row = cid>>3, ch = cid&7;
            const float* src = q + ((size_t)(h*NN + i0 + row))*D + ch*8;
            f32x4 a = *(const f32x4*)src, bb2 = *(const f32x4*)(src+4);
            *(short8v*)(aq + SWZ(row*128 + ch*16, row)) = cvt8(a,bb2);
        }
        for (int u=0;u<4;u++){
            int cid = t + 256*u; int row = cid>>3, ch = cid&7;
            int pos = pa + row; pos = pos < 0 ? 0 : pos;
            *(short8v*)(kb + SWZ(row*128 + ch*16, row)) =
                *(const short8v*)(kb16 + ((size_t)(hk*NN + pos))*D + ch*8);
        }
        __syncthreads();
        f32x4 acc[8];
        #pragma unroll
        for (int ct=0;ct<8;ct++) acc[ct] = (f32x4)0.f;
        #pragma unroll
        for (int ks=0;ks<2;ks++){
            int arow = w*16 + c;
            short8v af = *(short8v*)(aq + SWZ(arow*128 + ks*64 + lg*16, arow));
            #pragma unroll
            for (int ct=0;ct<8;ct++){
                int brow = ct*16 + c;
                short8v bf = *(short8v*)(kb + SWZ(brow*128 + ks*64 + lg*16, brow));
                acc[ct] = MFMA(af, bf, acc[ct]);
            }
        }
        #pragma unroll
        for (int ct=0;ct<8;ct++){
            int j = ct*16 + c;
            #pragma unroll
            for (int reg=0;reg<4;reg++){
                int tl2 = w*16 + lg*4 + reg;
                bool vis = (j >= tl2+1) && (j <= tl2+64) && (pa + j >= 0);
                float s = acc[ct][reg]*SCALE;
                acc[ct][reg] = vis ? s : NEGV;
            }
        }
        f32x4 mx = acc[0];
        #pragma unroll
        for (int ct=1;ct<8;ct++) mx = vmax4(mx, acc[ct]);
        #pragma unroll
        for (int o=1;o<16;o<<=1) mx = vmax4(mx, shflx4(mx,o));
        f32x4 sum = (f32x4)0.f;
        #pragma unroll
        for (int ct=0;ct<8;ct++){ acc[ct] = exp4(acc[ct]-mx); sum += acc[ct]; }
        #pragma unroll
        for (int o=1;o<16;o<<=1) sum += shflx4(sum,o);
        __syncthreads();
        #pragma unroll
        for (int ct=0;ct<8;ct++){
            #pragma unroll
            for (int reg=0;reg<4;reg++){
                int row = w*16 + lg*4 + reg;
                *(short*)(pl + SWZ(row*256 + (ct*16+c)*2, row)) = f2b(acc[ct][reg]);
            }
        }
        if (c==0){
            #pragma unroll
            for (int reg=0;reg<4;reg++) psl[w*16+lg*4+reg] = sum[reg];
        }
        __syncthreads();
        f32x4 pv[4];
        #pragma unroll
        for (int ctd=0;ctd<4;ctd++) pv[ctd] = (f32x4)0.f;
        #pragma unroll
        for (int ks=0;ks<4;ks++){
            int arow = w*16 + c;
            short8v pf = *(short8v*)(pl + SWZ(arow*256 + ks*64 + lg*16, arow));
            int pos0 = pa + ks*32 + lg*8;
            pos0 = pos0 < 0 ? 0 : pos0;
            #pragma unroll
            for (int ctd=0;ctd<4;ctd++){
                int d = ctd*16 + c;
                short8v bf = *(const short8v*)(vTg + ((size_t)(hk*64 + d))*NN + pos0);
                pv[ctd] = MFMA(pf, bf, pv[ctd]);
            }
        }
        #pragma unroll
        for (int ctd=0;ctd<4;ctd++)
            #pragma unroll
            for (int reg=0;reg<4;reg++){
                int row = w*16 + lg*4 + reg;
                float inv = 1.0f/psl[row];
                outs[((size_t)(h*NN + i0 + row))*D + ctd*16 + c] = f2b(pv[ctd][reg]*inv);
            }
        return;
    }
    {
        // ================= gates split-K partial GEMM =================
        int idx = b - 1024;
        char* ha = smem;
        char* bl = smem + 8192;
        int i0g = (idx & 31)*64, ky = idx >> 5;
        f32x4 acc[3];
        #pragma unroll
        for (int ct=0;ct<3;ct++) acc[ct] = (f32x4)0.f;
        for (int kc=0;kc<4;kc++){
            int kbase = ky*256 + kc*64;
            if (kc) __syncthreads();
            for (int u=0;u<2;u++){
                int cid = t + 256*u; int row = cid>>3, ch = cid&7;
                const float* src = hidden + (size_t)(i0g+row)*HID + kbase + ch*8;
                f32x4 a = *(const f32x4*)src, bb2 = *(const f32x4*)(src+4);
                *(short8v*)(ha + SWZ(row*128 + ch*16, row)) = cvt8(a,bb2);
            }
            for (int u=0;u<2;u++){
                int cid = t + 256*u;
                if (cid < 384){
                    int row = cid>>3, ch = cid&7;
                    *(short8v*)(bl + SWZ(row*128 + ch*16, row)) =
                        *(const short8v*)(cwb + (size_t)row*HID + kbase + ch*8);
                }
            }
            __syncthreads();
            #pragma unroll
            for (int ks=0;ks<2;ks++){
                int arow = w*16 + c;
                short8v af = *(short8v*)(ha + SWZ(arow*128 + ks*64 + lg*16, arow));
                #pragma unroll
                for (int ct=0;ct<3;ct++){
                    int brow = ct*16 + c;
                    short8v bf = *(short8v*)(bl + SWZ(brow*128 + ks*64 + lg*16, brow));
                    acc[ct] = MFMA(af, bf, acc[ct]);
                }
            }
        }
        #pragma unroll
        for (int ct=0;ct<3;ct++)
            #pragma unroll
            for (int reg=0;reg<4;reg++){
                int row = w*16 + lg*4 + reg;
                gpart[((size_t)ky*NN + i0g + row)*48 + ct*16 + c] = acc[ct][reg];
            }
    }
}

// ---------------------------------------------------------------------------
// K3: selected-block attention via MFMA + gate reduction (12 lanes) + gated combine.
__global__ __launch_bounds__(256) void k_selc(
    const float* __restrict__ q, const short* __restrict__ kbg, const short* __restrict__ vTg,
    const int* __restrict__ selidx,
    const short* __restrict__ outc, const short* __restrict__ outs,
    const float* __restrict__ gpart, const float* __restrict__ cbias,
    short* __restrict__ comb)
{
    __shared__ short pls[4][4*64];
    __shared__ float gsl[4][12];
    int i0 = blockIdx.x*4, hk = blockIdx.y, t = threadIdx.x;
    int wv = t>>6, lane = t&63;
    int i = i0 + wv;
    int c = lane&15, lg = lane>>4;
    int head = c & 3;

    int sel_r[4];
    #pragma unroll
    for (int nt=0;nt<4;nt++) sel_r[nt] = selidx[((size_t)(hk*NN + i))*NSEL + nt];

    short8v qa[2];
    #pragma unroll
    for (int ks=0;ks<2;ks++){
        const float* src = q + ((size_t)((hk*G + head)*NN + i))*D + ks*32 + lg*8;
        f32x4 a = *(const f32x4*)src, b = *(const f32x4*)(src+4);
        qa[ks] = cvt8(a,b);
    }

    f32x4 acc[4];
    #pragma unroll
    for (int nt=0;nt<4;nt++) acc[nt] = (f32x4)0.f;
    #pragma unroll
    for (int ks=0;ks<2;ks++){
        #pragma unroll
        for (int nt=0;nt<4;nt++){
            int pos = sel_r[nt]*CB + c;
            short8v bf = *(const short8v*)(kbg + ((size_t)(hk*NN + pos))*D + ks*32 + lg*8);
            acc[nt] = MFMA(qa[ks], bf, acc[nt]);
        }
    }
    #pragma unroll
    for (int nt=0;nt<4;nt++){
        int pos = sel_r[nt]*CB + c;
        f32x4 s = acc[nt]*SCALE;
        if (pos > i){ s[0]=NEGV; s[1]=NEGV; s[2]=NEGV; s[3]=NEGV; }
        acc[nt] = s;
    }
    f32x4 mx = acc[0];
    #pragma unroll
    for (int nt=1;nt<4;nt++) mx = vmax4(mx, acc[nt]);
    #pragma unroll
    for (int o=1;o<16;o<<=1) mx = vmax4(mx, shflx4(mx,o));
    f32x4 sum = (f32x4)0.f;
    #pragma unroll
    for (int nt=0;nt<4;nt++){ acc[nt] = exp4(acc[nt]-mx); sum += acc[nt]; }
    #pragma unroll
    for (int o=1;o<16;o<<=1) sum += shflx4(sum,o);

    if (lane < 16){
        #pragma unroll
        for (int nt=0;nt<4;nt++)
            #pragma unroll
            for (int reg=0;reg<4;reg++)
                pls[wv][reg*64 + nt*16 + lane] = f2b(acc[nt][reg]);
    }
    if (lane < 12){
        int o = hk*12 + lane;
        const float* gp0 = gpart + (size_t)i*48;
        float s = gp0[o] + gp0[(size_t)1*NN*48 + o]
                + gp0[(size_t)2*NN*48 + o] + gp0[(size_t)3*NN*48 + o] + cbias[o];
        gsl[wv][lane] = 1.0f/(1.0f+expf(-s));
    }
    __syncthreads();

    f32x4 pv[4];
    #pragma unroll
    for (int nt=0;nt<4;nt++) pv[nt] = (f32x4)0.f;
    #pragma unroll
    for (int ks=0;ks<2;ks++){
        short8v pa = *(const short8v*)(&pls[wv][head*64 + ks*32 + lg*8]);
        int sb = ks*2 + (lg>>1);
        int pos0 = sel_r[sb]*CB + (lg&1)*8;
        #pragma unroll
        for (int nt=0;nt<4;nt++){
            int d = nt*16 + c;
            short8v bf = *(const short8v*)(vTg + ((size_t)(hk*64 + d))*NN + pos0);
            pv[nt] = MFMA(pa, bf, pv[nt]);
        }
    }

    f32x4 myv = (lg==0) ? pv[0] : (lg==1) ? pv[1] : (lg==2) ? pv[2] : pv[3];
    int d = lg*16 + c;
    #pragma unroll
    for (int reg=0;reg<4;reg++){
        float g0 = gsl[wv][reg*3+0], g1 = gsl[wv][reg*3+1], g2 = gsl[wv][reg*3+2];
        size_t off = ((size_t)((hk*G+reg)*NN + i))*D + d;
        float fo = myv[reg] * (1.0f/sum[reg]);
        float val = g0*b2f(outc[off]) + g1*fo + g2*b2f(outs[off]);
        comb[(size_t)i*HID + (hk*G+reg)*64 + d] = f2b(val);
    }
}

// ---------------------------------------------------------------------------
// K4: out = comb @ wb^T (unchanged)
__global__ __launch_bounds__(256) void k_gemm(
    const short* __restrict__ A, const short* __restrict__ Bw, float* __restrict__ out)
{
    __shared__ char ab[2][64*128];
    __shared__ char bb[2][64*128];
    int m0 = blockIdx.x*64, n0 = blockIdx.y*64, t = threadIdx.x;
    int w = t>>6, lane = t&63, c = lane&15, lg = lane>>4;
    int r0 = t>>3, ch0 = t&7;
    f32x4 acc[4];
    #pragma unroll
    for (int ct=0;ct<4;ct++) acc[ct] = (f32x4)0.f;
    const short* Ap = A  + (size_t)(m0+r0)*HID + ch0*8;
    const short* Bp = Bw + (size_t)(n0+r0)*HID + ch0*8;
    short8v ra0 = *(const short8v*)(Ap);
    short8v ra1 = *(const short8v*)(Ap + 32*HID);
    short8v rb0 = *(const short8v*)(Bp);
    short8v rb1 = *(const short8v*)(Bp + 32*HID);
    for (int kc=0;kc<16;kc++){
        char* abuf = ab[kc&1];
        char* bbuf = bb[kc&1];
        *(short8v*)(abuf + SWZ(r0*128 + ch0*16, r0)) = ra0;
        *(short8v*)(abuf + SWZ((r0+32)*128 + ch0*16, r0+32)) = ra1;
        *(short8v*)(bbuf + SWZ(r0*128 + ch0*16, r0)) = rb0;
        *(short8v*)(bbuf + SWZ((r0+32)*128 + ch0*16, r0+32)) = rb1;
        __syncthreads();
        if (kc < 15){
            const short* Ap2 = Ap + (kc+1)*64;
            const short* Bp2 = Bp + (kc+1)*64;
            ra0 = *(const short8v*)(Ap2);
            ra1 = *(const short8v*)(Ap2 + 32*HID);
            rb0 = *(const short8v*)(Bp2);
            rb1 = *(const short8v*)(Bp2 + 32*HID);
        }
        #pragma unroll
        for (int ks=0;ks<2;ks++){
            int arow = w*16 + c;
            short8v af = *(short8v*)(abuf + SWZ(arow*128 + ks*64 + lg*16, arow));
            #pragma unroll
            for (int ct=0;ct<4;ct++){
                int brow = ct*16 + c;
                short8v bf = *(short8v*)(bbuf + SWZ(brow*128 + ks*64 + lg*16, brow));
                acc[ct] = MFMA(af, bf, acc[ct]);
            }
        }
    }
    #pragma unroll
    for (int ct=0;ct<4;ct++)
        #pragma unroll
        for (int reg=0;reg<4;reg++){
            int row = w*16 + lg*4 + reg;
            out[((size_t)(m0+row))*HID + n0 + ct*16 + c] = acc[ct][reg];
        }
}

// ---------------------------------------------------------------------------
extern "C" void kernel_launch(void* const* d_in, const int* in_sizes, int n_in,
                              void* d_out, int out_size, void* d_ws, size_t ws_size,
                              hipStream_t stream)
{
    const float* hidden     = (const float*)d_in[0];
    const float* q          = (const float*)d_in[1];
    const float* k          = (const float*)d_in[2];
    const float* v          = (const float*)d_in[3];
    const float* memkv      = (const float*)d_in[4];
    const float* ksc        = (const float*)d_in[5];
    const float* vsc        = (const float*)d_in[6];
    const float* combiner_w = (const float*)d_in[7];
    const float* combiner_b = (const float*)d_in[8];
    const float* combine_w  = (const float*)d_in[9];
    float* out = (float*)d_out;

    char* p = (char*)d_ws;
    short* ckb  = (short*)p; p += (size_t)HKV*144*64*2;
    short* cvtg = (short*)p; p += (size_t)HKV*64*160*2;
    short* wbg  = (short*)p; p += (size_t)HID*HID*2;
    short* cwbg = (short*)p; p += (size_t)48*HID*2;
    short* kbg  = (short*)p; p += (size_t)HKV*NN*D*2;
    short* vTg  = (short*)p; p += (size_t)HKV*64*NN*2;
    short* outc = (short*)p; p += (size_t)H*NN*D*2;
    short* outs = (short*)p; p += (size_t)H*NN*D*2;
    float* gpart= (float*)p; p += (size_t)4*NN*48*4;
    short* comb = (short*)p; p += (size_t)NN*HID*2;
    int*  selix = (int*)p;   p += (size_t)HKV*NN*NSEL*4;

    k_prep <<<848, 256, 0, stream>>>(combiner_w, k, v, memkv, ksc, vsc,
                                      cwbg, kbg, vTg, ckb, cvtg);
    k_attn <<<2176, 256, 0, stream>>>(q, ckb, cvtg, outc, selix,
                                       kbg, vTg, outs, hidden, cwbg, gpart,
                                       combine_w, wbg);
    k_selc <<<dim3(NN/4, HKV), 256, 0, stream>>>(q, kbg, vTg, selix, outc, outs,
                                                  gpart, combiner_b, comb);
    k_gemm <<<dim3(NN/64, HID/64), 256, 0, stream>>>(comb, wbg, out);
}

// Round 18
// 61.795 us; speedup vs baseline: 1.1305x; 1.0119x over previous
//
#include <hip/hip_runtime.h>
#include <hip/hip_bf16.h>
#include <math.h>

#define H    16
#define HKV  4
#define G    4
#define NN   2048
#define D    64
#define HID  1024
#define CB   16
#define W    128
#define NSEL 4
#define WIN  64
#define NEGV -1e10f
#define SCALE 0.125f

typedef __attribute__((ext_vector_type(4))) float f32x4;
typedef __attribute__((ext_vector_type(4))) short short4v;
typedef __attribute__((ext_vector_type(8))) short short8v;

__device__ inline short f2b(float x){
    __hip_bfloat16 h = __float2bfloat16(x);
    return *reinterpret_cast<short*>(&h);
}
__device__ inline float b2f(short s){
    unsigned u = ((unsigned)(unsigned short)s) << 16;
    return __builtin_bit_cast(float, u);
}
__device__ inline short8v cvt8(f32x4 a, f32x4 b){
    short8v r;
    r[0]=f2b(a[0]); r[1]=f2b(a[1]); r[2]=f2b(a[2]); r[3]=f2b(a[3]);
    r[4]=f2b(b[0]); r[5]=f2b(b[1]); r[6]=f2b(b[2]); r[7]=f2b(b[3]);
    return r;
}
#define SWZ(byte, row) ((byte) ^ (((row)&7)<<4))
#define MFMA(a,b,c) __builtin_amdgcn_mfma_f32_16x16x32_bf16(a,b,c,0,0,0)

__device__ inline float wave_sum(float x){ for(int o=32;o;o>>=1) x += __shfl_xor(x,o); return x; }

__device__ inline f32x4 vmax4(f32x4 a, f32x4 b){
    f32x4 r; r[0]=fmaxf(a[0],b[0]); r[1]=fmaxf(a[1],b[1]); r[2]=fmaxf(a[2],b[2]); r[3]=fmaxf(a[3],b[3]); return r;
}
__device__ inline f32x4 shflx4(f32x4 x, int o){
    f32x4 r; r[0]=__shfl_xor(x[0],o); r[1]=__shfl_xor(x[1],o); r[2]=__shfl_xor(x[2],o); r[3]=__shfl_xor(x[3],o); return r;
}
__device__ inline f32x4 exp4(f32x4 x){
    f32x4 r; r[0]=expf(x[0]); r[1]=expf(x[1]); r[2]=expf(x[2]); r[3]=expf(x[3]); return r;
}

// ---------------------------------------------------------------------------
// K1: fused prep (combine_w conversion lives in k_attn tail). 848 blocks.
__device__ inline void conv_seg(const float* __restrict__ src, short* __restrict__ dst,
                                int b, int t){
    size_t idx = (size_t)b*1024 + t*4;
    f32x4 a = *(const f32x4*)(src + idx);
    short4v r; r[0]=f2b(a[0]); r[1]=f2b(a[1]); r[2]=f2b(a[2]); r[3]=f2b(a[3]);
    *(short4v*)(dst + idx) = r;
}

__global__ __launch_bounds__(256) void k_prep(
    const float* __restrict__ combiner_w,
    const float* __restrict__ k, const float* __restrict__ v,
    const float* __restrict__ memkv, const float* __restrict__ ksc, const float* __restrict__ vsc,
    short* __restrict__ cwb, short* __restrict__ kb16,
    short* __restrict__ vT, short* __restrict__ ckb, short* __restrict__ cvtg)
{
    int b = blockIdx.x, t = threadIdx.x;
    if (b < 48){ conv_seg(combiner_w, cwb, b, t); return; }
    b -= 48;
    if (b < 512){ conv_seg(k, kb16, b, t); return; }
    b -= 512;
    if (b < 128){
        __shared__ float tl[64][65];
        int hk = b>>5, i0 = (b&31)*64;
        for (int u=0;u<4;u++){
            int cid = t + 256*u; int r = cid>>4, ch = cid&15;
            f32x4 a = *(const f32x4*)(v + ((size_t)(hk*NN + i0 + r))*D + ch*4);
            tl[r][ch*4+0]=a[0]; tl[r][ch*4+1]=a[1]; tl[r][ch*4+2]=a[2]; tl[r][ch*4+3]=a[3];
        }
        __syncthreads();
        int d = t>>2, qd = t&3;
        short8v p0, p1;
        #pragma unroll
        for (int e=0;e<8;e++) p0[e] = f2b(tl[qd*16+e][d]);
        #pragma unroll
        for (int e=0;e<8;e++) p1[e] = f2b(tl[qd*16+8+e][d]);
        short* dst = vT + ((size_t)(hk*64 + d))*NN + i0 + qd*16;
        *(short8v*)dst = p0;
        *(short8v*)(dst+8) = p1;
        return;
    }
    b -= 128;
    {
        int j = b;
        int hk = t>>6, d = t&63;
        if (j > 128){
            if (j < 144) ckb[((size_t)(hk*144 + j))*64 + d] = 0;
            cvtg[((size_t)(hk*64 + d))*160 + j] = 0;
            return;
        }
        float xk, xv;
        if (j==0){ xk = memkv[(0*HKV+hk)*D + d]; xv = memkv[(HKV+hk)*D + d]; }
        else {
            int jb = j-1;
            const float* kp = k + ((size_t)(hk*NN + jb*CB))*D + d;
            const float* vp = v + ((size_t)(hk*NN + jb*CB))*D + d;
            float sk=0.f, sv=0.f;
            #pragma unroll
            for (int tt=0;tt<CB;tt++){ sk += kp[tt*D]; sv += vp[tt*D]; }
            xk = sk*(1.0f/CB); xv = sv*(1.0f/CB);
            float msk = wave_sum(xk*xk)*(1.0f/D);
            float msv = wave_sum(xv*xv)*(1.0f/D);
            xk = xk*rsqrtf(msk+1e-6f)*ksc[d];
            xv = xv*rsqrtf(msv+1e-6f)*vsc[d];
        }
        ckb[((size_t)(hk*144 + j))*64 + d] = f2b(xk);
        cvtg[((size_t)(hk*64 + d))*160 + j] = f2b(xv);
    }
}

// ---------------------------------------------------------------------------
// K2: fused attention stage. cattn (0..511) + swin (512..1023) + gates split-K
// (1024..1151) + combine_w conversion tail (1152..2175).
// LDS 24576 B -> 6 blocks/CU. Column j=128 of cattn is provably always masked:
// dropped 9th accumulator / CK rows 128+ / PV ks=4. psl removed (sum is lane-local).
// Wave-private-only barriers removed (3 -> 2 per branch).
__global__ __launch_bounds__(256, 6) void k_attn(
    const float* __restrict__ q, const short* __restrict__ ckb, const short* __restrict__ cvt_g,
    short* __restrict__ outc, int* __restrict__ selidx,
    const short* __restrict__ kb16, const short* __restrict__ vTg, short* __restrict__ outs,
    const float* __restrict__ hidden, const short* __restrict__ cwb,
    float* __restrict__ gpart,
    const float* __restrict__ combine_w, short* __restrict__ wbg)
{
    __shared__ char smem[24576];
    int b = blockIdx.x, t = threadIdx.x;
    int w = t>>6, lane = t&63, c = lane&15, lg = lane>>4;

    if (b >= 1152){ conv_seg(combine_w, wbg, b - 1152, t); return; }

    if (b < 512){
        // ================= compressed attention + importance + top-k =================
        char* aq  = smem;                      // staging: 8192
        char* ckl = smem + 8192;               // staging: 128 rows * 128 B = 16384 (ends 24576)
        char* pl  = smem;                      // post-barrier: 64 rows * 256 B = 16384
        float* impl = (float*)(smem + 16384);  // post-barrier: 8192 (ends 24576)
        int hk = b & 3, i0 = (b >> 2)*16;
        const short* cvhk = cvt_g + (size_t)hk*64*160;

        for (int u=0;u<2;u++){
            int cid = t + 256*u; int row = cid>>3, ch = cid&7;
            const float* src = q + ((size_t)((hk*G + (row&3))*NN + i0 + (row>>2)))*D + ch*8;
            f32x4 a = *(const f32x4*)src, bb2 = *(const f32x4*)(src+4);
            *(short8v*)(aq + SWZ(row*128 + ch*16, row)) = cvt8(a,bb2);
        }
        for (int u=0;u<4;u++){
            int cid = t + 256*u; int row = cid>>3, ch = cid&7;
            const short* src = ckb + ((size_t)(hk*144 + row))*64 + ch*8;
            *(short8v*)(ckl + SWZ(row*128 + ch*16, row)) = *(const short8v*)src;
        }
        __syncthreads();

        f32x4 acc[8];
        #pragma unroll
        for (int ct=0;ct<8;ct++) acc[ct] = (f32x4)0.f;
        #pragma unroll
        for (int ks=0;ks<2;ks++){
            int arow = w*16 + c;
            short8v af = *(short8v*)(aq + SWZ(arow*128 + ks*64 + lg*16, arow));
            #pragma unroll
            for (int ct=0;ct<8;ct++){
                int row = ct*16 + c;
                short8v bf = *(short8v*)(ckl + SWZ(row*128 + ks*64 + lg*16, row));
                acc[ct] = MFMA(af, bf, acc[ct]);
            }
        }

        // mask + scale; importance in registers across the barrier
        f32x4 sum;
        float imp8[8];
        int tloc = w*4 + lg;
        {
            int ii = i0 + tloc;
            #pragma unroll
            for (int ct=0;ct<8;ct++){
                int j = ct*16 + c;
                bool vis = (j==0) || (j*16 <= ii);
                f32x4 s = acc[ct]*SCALE;
                if (!vis){ s[0]=NEGV; s[1]=NEGV; s[2]=NEGV; s[3]=NEGV; }
                acc[ct] = s;
            }
            #pragma unroll
            for (int ct=0;ct<8;ct++){
                f32x4 s = acc[ct];
                imp8[ct] = 0.25f*(s[0]+s[1]+s[2]+s[3]);
            }
            f32x4 mx = acc[0];
            #pragma unroll
            for (int ct=1;ct<8;ct++) mx = vmax4(mx, acc[ct]);
            #pragma unroll
            for (int o=1;o<16;o<<=1) mx = vmax4(mx, shflx4(mx,o));
            sum = (f32x4)0.f;
            #pragma unroll
            for (int ct=0;ct<8;ct++){ acc[ct] = exp4(acc[ct]-mx); sum += acc[ct]; }
            #pragma unroll
            for (int o=1;o<16;o<<=1) sum += shflx4(sum,o);
        }
        __syncthreads();   // all QK reads of aq/ckl done; region becomes pl/impl

        #pragma unroll
        for (int ct=0;ct<8;ct++){
            #pragma unroll
            for (int reg=0;reg<4;reg++){
                int row = w*16 + lg*4 + reg;
                *(short*)(pl + SWZ(row*256 + (ct*16+c)*2, row)) = f2b(acc[ct][reg]);
            }
        }
        #pragma unroll
        for (int ct=0;ct<8;ct++){
            int j = ct*16 + c;
            if (j>=1) impl[tloc*128 + (j-1)] = imp8[ct];
        }
        if (c==0) impl[tloc*128 + 127] = NEGV;   // block 127 always masked (j=128 never visible)

        // top-k: 4 tokens in parallel (wave-private impl rows; no barrier needed)
        {
            int tt = w*4 + lg;
            int sl = c;
            float vals[8];
            #pragma unroll
            for (int e=0;e<8;e++) vals[e] = impl[tt*128 + sl*8 + e];
            int sel[4];
            #pragma unroll
            for (int r4=0;r4<4;r4++){
                float bv = -INFINITY; int bj = 0;
                #pragma unroll
                for (int e=0;e<8;e++){
                    if (vals[e] > bv){ bv = vals[e]; bj = sl*8+e; }
                }
                #pragma unroll
                for (int o=1;o<16;o<<=1){
                    float ov = __shfl_xor(bv,o);
                    int oj = __shfl_xor(bj,o);
                    if (ov > bv || (ov==bv && oj<bj)){ bv=ov; bj=oj; }
                }
                sel[r4] = bj;
                if (sl == (bj>>3)){
                    #pragma unroll
                    for (int e=0;e<8;e++) if (e == (bj&7)) vals[e] = -INFINITY;
                }
            }
            if (sl == 0){
                int* sp = selidx + ((size_t)(hk*NN + i0 + tt))*NSEL;
                sp[0]=sel[0]; sp[1]=sel[1]; sp[2]=sel[2]; sp[3]=sel[3];
            }
        }

        f32x4 pv[4];
        #pragma unroll
        for (int ctd=0;ctd<4;ctd++) pv[ctd] = (f32x4)0.f;
        #pragma unroll
        for (int ks=0;ks<4;ks++){
            int arow = w*16 + c;
            short8v pf = *(short8v*)(pl + SWZ(arow*256 + ks*64 + lg*16, arow));
            #pragma unroll
            for (int ctd=0;ctd<4;ctd++){
                int row = ctd*16 + c;
                short8v bf = *(const short8v*)(cvhk + (size_t)row*160 + ks*32 + lg*8);
                pv[ctd] = MFMA(pf, bf, pv[ctd]);
            }
        }
        #pragma unroll
        for (int ctd=0;ctd<4;ctd++)
            #pragma unroll
            for (int reg=0;reg<4;reg++){
                int row = w*16 + lg*4 + reg;
                float inv = 1.0f/sum[reg];
                int hh = hk*G + reg;
                int ii = i0 + (row>>2);
                outc[((size_t)(hh*NN + ii))*D + ctd*16 + c] = f2b(pv[ctd][reg]*inv);
            }
        return;
    }
    if (b < 1024){
        // ================= sliding-window attention =================
        int idx = b - 512;
        char* aq = smem;                       // 8192
        char* kb = smem + 8192;                // 16384 (ends 24576); pl aliases kb
        char* pl = kb;
        int i0 = (idx & 31)*64, h = idx >> 5;
        int hk = h >> 2;
        int pa = i0 - 64;
        for (int u=0;u<2;u++){
            int cid = t + 256*u; int row = cid>>3, ch = cid&7;
            const float* src = q + ((size_t)(h*NN + i0 + row))*D + ch*8;
            f32x4 a = *(const f32x4*)src, bb2 = *(const f32x4*)(src+4);
            *(short8v*)(aq + SWZ(row*128 + ch*16, row)) = cvt8(a,bb2);
        }
        for (int u=0;u<4;u++){
            int cid = t + 256*u; int row = cid>>3, ch = cid&7;
            int pos = pa + row; pos = pos < 0 ? 0 : pos;
            *(short8v*)(kb + SWZ(row*128 + ch*16, row)) =
                *(const short8v*)(kb16 + ((size_t)(hk*NN + pos))*D + ch*8);
        }
        __syncthreads();
        f32x4 acc[8];
        #pragma unroll
        for (int ct=0;ct<8;ct++) acc[ct] = (f32x4)0.f;
        #pragma unroll
        for (int ks=0;ks<2;ks++){
            int arow = w*16 + c;
            short8v af = *(short8v*)(aq + SWZ(arow*128 + ks*64 + lg*16, arow));
            #pragma unroll
            for (int ct=0;ct<8;ct++){
                int brow = ct*16 + c;
                short8v bf = *(short8v*)(kb + SWZ(brow*128 + ks*64 + lg*16, brow));
                acc[ct] = MFMA(af, bf, acc[ct]);
            }
        }
        #pragma unroll
        for (int ct=0;ct<8;ct++){
            int j = ct*16 + c;
            #pragma unroll
            for (int reg=0;reg<4;reg++){
                int tl2 = w*16 + lg*4 + reg;
                bool vis = (j >= tl2+1) && (j <= tl2+64) && (pa + j >= 0);
                float s = acc[ct][reg]*SCALE;
                acc[ct][reg] = vis ? s : NEGV;
            }
        }
        f32x4 mx = acc[0];
        #pragma unroll
        for (int ct=1;ct<8;ct++) mx = vmax4(mx, acc[ct]);
        #pragma unroll
        for (int o=1;o<16;o<<=1) mx = vmax4(mx, shflx4(mx,o));
        f32x4 sum = (f32x4)0.f;
        #pragma unroll
        for (int ct=0;ct<8;ct++){ acc[ct] = exp4(acc[ct]-mx); sum += acc[ct]; }
        #pragma unroll
        for (int o=1;o<16;o<<=1) sum += shflx4(sum,o);
        __syncthreads();   // all waves done reading kb before P overwrites it
        #pragma unroll
        for (int ct=0;ct<8;ct++){
            #pragma unroll
            for (int reg=0;reg<4;reg++){
                int row = w*16 + lg*4 + reg;
                *(short*)(pl + SWZ(row*256 + (ct*16+c)*2, row)) = f2b(acc[ct][reg]);
            }
        }
        // P rows are wave-private: no barrier before PV
        f32x4 pv[4];
        #pragma unroll
        for (int ctd=0;ctd<4;ctd++) pv[ctd] = (f32x4)0.f;
        #pragma unroll
        for (int ks=0;ks<4;ks++){
            int arow = w*16 + c;
            short8v pf = *(short8v*)(pl + SWZ(arow*256 + ks*64 + lg*16, arow));
            int pos0 = pa + ks*32 + lg*8;
            pos0 = pos0 < 0 ? 0 : pos0;
            #pragma unroll
            for (int ctd=0;ctd<4;ctd++){
                int d = ctd*16 + c;
                short8v bf = *(const short8v*)(vTg + ((size_t)(hk*64 + d))*NN + pos0);
                pv[ctd] = MFMA(pf, bf, pv[ctd]);
            }
        }
        #pragma unroll
        for (int ctd=0;ctd<4;ctd++)
            #pragma unroll
            for (int reg=0;reg<4;reg++){
                int row = w*16 + lg*4 + reg;
                float inv = 1.0f/sum[reg];
                outs[((size_t)(h*NN + i0 + row))*D + ctd*16 + c] = f2b(pv[ctd][reg]*inv);
            }
        return;
    }
    {
        // ================= gates split-K partial GEMM =================
        int idx = b - 1024;
        char* ha = smem;
        char* bl = smem + 8192;
        int i0g = (idx & 31)*64, ky = idx >> 5;
        f32x4 acc[3];
        #pragma unroll
        for (int ct=0;ct<3;ct++) acc[ct] = (f32x4)0.f;
        for (int kc=0;kc<4;kc++){
            int kbase = ky*256 + kc*64;
            if (kc) __syncthreads();
            for (int u=0;u<2;u++){
                int cid = t + 256*u; int row = cid>>3, ch = cid&7;
                const float* src = hidden + (size_t)(i0g+row)*HID + kbase + ch*8;
                f32x4 a = *(const f32x4*)src, bb2 = *(const f32x4*)(src+4);
                *(short8v*)(ha + SWZ(row*128 + ch*16, row)) = cvt8(a,bb2);
            }
            for (int u=0;u<2;u++){
                int cid = t + 256*u;
                if (cid < 384){
                    int row = cid>>3, ch = cid&7;
                    *(short8v*)(bl + SWZ(row*128 + ch*16, row)) =
                        *(const short8v*)(cwb + (size_t)row*HID + kbase + ch*8);
                }
            }
            __syncthreads();
            #pragma unroll
            for (int ks=0;ks<2;ks++){
                int arow = w*16 + c;
                short8v af = *(short8v*)(ha + SWZ(arow*128 + ks*64 + lg*16, arow));
                #pragma unroll
                for (int ct=0;ct<3;ct++){
                    int brow = ct*16 + c;
                    short8v bf = *(short8v*)(bl + SWZ(brow*128 + ks*64 + lg*16, brow));
                    acc[ct] = MFMA(af, bf, acc[ct]);
                }
            }
        }
        #pragma unroll
        for (int ct=0;ct<3;ct++)
            #pragma unroll
            for (int reg=0;reg<4;reg++){
                int row = w*16 + lg*4 + reg;
                gpart[((size_t)ky*NN + i0g + row)*48 + ct*16 + c] = acc[ct][reg];
            }
    }
}

// ---------------------------------------------------------------------------
// K3: selected-block attention via MFMA + gate reduction (12 lanes) + gated combine.
__global__ __launch_bounds__(256) void k_selc(
    const float* __restrict__ q, const short* __restrict__ kbg, const short* __restrict__ vTg,
    const int* __restrict__ selidx,
    const short* __restrict__ outc, const short* __restrict__ outs,
    const float* __restrict__ gpart, const float* __restrict__ cbias,
    short* __restrict__ comb)
{
    __shared__ short pls[4][4*64];
    __shared__ float gsl[4][12];
    int i0 = blockIdx.x*4, hk = blockIdx.y, t = threadIdx.x;
    int wv = t>>6, lane = t&63;
    int i = i0 + wv;
    int c = lane&15, lg = lane>>4;
    int head = c & 3;

    int sel_r[4];
    #pragma unroll
    for (int nt=0;nt<4;nt++) sel_r[nt] = selidx[((size_t)(hk*NN + i))*NSEL + nt];

    short8v qa[2];
    #pragma unroll
    for (int ks=0;ks<2;ks++){
        const float* src = q + ((size_t)((hk*G + head)*NN + i))*D + ks*32 + lg*8;
        f32x4 a = *(const f32x4*)src, b = *(const f32x4*)(src+4);
        qa[ks] = cvt8(a,b);
    }

    f32x4 acc[4];
    #pragma unroll
    for (int nt=0;nt<4;nt++) acc[nt] = (f32x4)0.f;
    #pragma unroll
    for (int ks=0;ks<2;ks++){
        #pragma unroll
        for (int nt=0;nt<4;nt++){
            int pos = sel_r[nt]*CB + c;
            short8v bf = *(const short8v*)(kbg + ((size_t)(hk*NN + pos))*D + ks*32 + lg*8);
            acc[nt] = MFMA(qa[ks], bf, acc[nt]);
        }
    }
    #pragma unroll
    for (int nt=0;nt<4;nt++){
        int pos = sel_r[nt]*CB + c;
        f32x4 s = acc[nt]*SCALE;
        if (pos > i){ s[0]=NEGV; s[1]=NEGV; s[2]=NEGV; s[3]=NEGV; }
        acc[nt] = s;
    }
    f32x4 mx = acc[0];
    #pragma unroll
    for (int nt=1;nt<4;nt++) mx = vmax4(mx, acc[nt]);
    #pragma unroll
    for (int o=1;o<16;o<<=1) mx = vmax4(mx, shflx4(mx,o));
    f32x4 sum = (f32x4)0.f;
    #pragma unroll
    for (int nt=0;nt<4;nt++){ acc[nt] = exp4(acc[nt]-mx); sum += acc[nt]; }
    #pragma unroll
    for (int o=1;o<16;o<<=1) sum += shflx4(sum,o);

    if (lane < 16){
        #pragma unroll
        for (int nt=0;nt<4;nt++)
            #pragma unroll
            for (int reg=0;reg<4;reg++)
                pls[wv][reg*64 + nt*16 + lane] = f2b(acc[nt][reg]);
    }
    if (lane < 12){
        int o = hk*12 + lane;
        const float* gp0 = gpart + (size_t)i*48;
        float s = gp0[o] + gp0[(size_t)1*NN*48 + o]
                + gp0[(size_t)2*NN*48 + o] + gp0[(size_t)3*NN*48 + o] + cbias[o];
        gsl[wv][lane] = 1.0f/(1.0f+expf(-s));
    }
    __syncthreads();

    f32x4 pv[4];
    #pragma unroll
    for (int nt=0;nt<4;nt++) pv[nt] = (f32x4)0.f;
    #pragma unroll
    for (int ks=0;ks<2;ks++){
        short8v pa = *(const short8v*)(&pls[wv][head*64 + ks*32 + lg*8]);
        int sb = ks*2 + (lg>>1);
        int pos0 = sel_r[sb]*CB + (lg&1)*8;
        #pragma unroll
        for (int nt=0;nt<4;nt++){
            int d = nt*16 + c;
            short8v bf = *(const short8v*)(vTg + ((size_t)(hk*64 + d))*NN + pos0);
            pv[nt] = MFMA(pa, bf, pv[nt]);
        }
    }

    f32x4 myv = (lg==0) ? pv[0] : (lg==1) ? pv[1] : (lg==2) ? pv[2] : pv[3];
    int d = lg*16 + c;
    #pragma unroll
    for (int reg=0;reg<4;reg++){
        float g0 = gsl[wv][reg*3+0], g1 = gsl[wv][reg*3+1], g2 = gsl[wv][reg*3+2];
        size_t off = ((size_t)((hk*G+reg)*NN + i))*D + d;
        float fo = myv[reg] * (1.0f/sum[reg]);
        float val = g0*b2f(outc[off]) + g1*fo + g2*b2f(outs[off]);
        comb[(size_t)i*HID + (hk*G+reg)*64 + d] = f2b(val);
    }
}

// ---------------------------------------------------------------------------
// K4: out = comb @ wb^T (unchanged)
__global__ __launch_bounds__(256) void k_gemm(
    const short* __restrict__ A, const short* __restrict__ Bw, float* __restrict__ out)
{
    __shared__ char ab[2][64*128];
    __shared__ char bb[2][64*128];
    int m0 = blockIdx.x*64, n0 = blockIdx.y*64, t = threadIdx.x;
    int w = t>>6, lane = t&63, c = lane&15, lg = lane>>4;
    int r0 = t>>3, ch0 = t&7;
    f32x4 acc[4];
    #pragma unroll
    for (int ct=0;ct<4;ct++) acc[ct] = (f32x4)0.f;
    const short* Ap = A  + (size_t)(m0+r0)*HID + ch0*8;
    const short* Bp = Bw + (size_t)(n0+r0)*HID + ch0*8;
    short8v ra0 = *(const short8v*)(Ap);
    short8v ra1 = *(const short8v*)(Ap + 32*HID);
    short8v rb0 = *(const short8v*)(Bp);
    short8v rb1 = *(const short8v*)(Bp + 32*HID);
    for (int kc=0;kc<16;kc++){
        char* abuf = ab[kc&1];
        char* bbuf = bb[kc&1];
        *(short8v*)(abuf + SWZ(r0*128 + ch0*16, r0)) = ra0;
        *(short8v*)(abuf + SWZ((r0+32)*128 + ch0*16, r0+32)) = ra1;
        *(short8v*)(bbuf + SWZ(r0*128 + ch0*16, r0)) = rb0;
        *(short8v*)(bbuf + SWZ((r0+32)*128 + ch0*16, r0+32)) = rb1;
        __syncthreads();
        if (kc < 15){
            const short* Ap2 = Ap + (kc+1)*64;
            const short* Bp2 = Bp + (kc+1)*64;
            ra0 = *(const short8v*)(Ap2);
            ra1 = *(const short8v*)(Ap2 + 32*HID);
            rb0 = *(const short8v*)(Bp2);
            rb1 = *(const short8v*)(Bp2 + 32*HID);
        }
        #pragma unroll
        for (int ks=0;ks<2;ks++){
            int arow = w*16 + c;
            short8v af = *(short8v*)(abuf + SWZ(arow*128 + ks*64 + lg*16, arow));
            #pragma unroll
            for (int ct=0;ct<4;ct++){
                int brow = ct*16 + c;
                short8v bf = *(short8v*)(bbuf + SWZ(brow*128 + ks*64 + lg*16, brow));
                acc[ct] = MFMA(af, bf, acc[ct]);
            }
        }
    }
    #pragma unroll
    for (int ct=0;ct<4;ct++)
        #pragma unroll
        for (int reg=0;reg<4;reg++){
            int row = w*16 + lg*4 + reg;
            out[((size_t)(m0+row))*HID + n0 + ct*16 + c] = acc[ct][reg];
        }
}

// ---------------------------------------------------------------------------
extern "C" void kernel_launch(void* const* d_in, const int* in_sizes, int n_in,
                              void* d_out, int out_size, void* d_ws, size_t ws_size,
                              hipStream_t stream)
{
    const float* hidden     = (const float*)d_in[0];
    const float* q          = (const float*)d_in[1];
    const float* k          = (const float*)d_in[2];
    const float* v          = (const float*)d_in[3];
    const float* memkv      = (const float*)d_in[4];
    const float* ksc        = (const float*)d_in[5];
    const float* vsc        = (const float*)d_in[6];
    const float* combiner_w = (const float*)d_in[7];
    const float* combiner_b = (const float*)d_in[8];
    const float* combine_w  = (const float*)d_in[9];
    float* out = (float*)d_out;

    char* p = (char*)d_ws;
    short* ckb  = (short*)p; p += (size_t)HKV*144*64*2;
    short* cvtg = (short*)p; p += (size_t)HKV*64*160*2;
    short* wbg  = (short*)p; p += (size_t)HID*HID*2;
    short* cwbg = (short*)p; p += (size_t)48*HID*2;
    short* kbg  = (short*)p; p += (size_t)HKV*NN*D*2;
    short* vTg  = (short*)p; p += (size_t)HKV*64*NN*2;
    short* outc = (short*)p; p += (size_t)H*NN*D*2;
    short* outs = (short*)p; p += (size_t)H*NN*D*2;
    float* gpart= (float*)p; p += (size_t)4*NN*48*4;
    short* comb = (short*)p; p += (size_t)NN*HID*2;
    int*  selix = (int*)p;   p += (size_t)HKV*NN*NSEL*4;

    k_prep <<<848, 256, 0, stream>>>(combiner_w, k, v, memkv, ksc, vsc,
                                      cwbg, kbg, vTg, ckb, cvtg);
    k_attn <<<2176, 256, 0, stream>>>(q, ckb, cvtg, outc, selix,
                                       kbg, vTg, outs, hidden, cwbg, gpart,
                                       combine_w, wbg);
    k_selc <<<dim3(NN/4, HKV), 256, 0, stream>>>(q, kbg, vTg, selix, outc, outs,
                                                  gpart, combiner_b, comb);
    k_gemm <<<dim3(NN/64, HID/64), 256, 0, stream>>>(comb, wbg, out);
}